// Round 10
// baseline (1210.913 us; speedup 1.0000x reference)
//
#include <hip/hip_runtime.h>
#include <stdint.h>
#include <stddef.h>

// RNN_arch_2_final: 3-cell stacked RNN, T=16, B=16384, hidden 256.
// R10: 256-thread WGs (4 waves, 32-row tile), grid 512 -> 2 barrier-
// DECOUPLED WGs per CU (LDS 2x~72KB fits; 2 waves/SIMD from DIFFERENT WGs
// so one WG's barrier drain is hidden by the other's issue stream).
// Swapped-operand MFMA, NT streaming, folded feed/h4/cue/o1s/o2s, rcp-tanh.

#define BN 16384
#define TT 16

typedef short s16x8 __attribute__((ext_vector_type(8)));
typedef short s16x4 __attribute__((ext_vector_type(4)));
typedef float f32x4 __attribute__((ext_vector_type(4)));

#define MFMA(a, b, c) __builtin_amdgcn_mfma_f32_16x16x32_bf16((a), (b), (c), 0, 0, 0)

__device__ __forceinline__ short f2bf(float f) {
  union { float f; uint32_t u; } v; v.f = f;
  uint32_t u = v.u;
  u += 0x7FFFu + ((u >> 16) & 1u);   // RNE
  return (short)(u >> 16);
}
__device__ __forceinline__ float bf2f(short s) {
  union { uint32_t u; float f; } v; v.u = ((uint32_t)(uint16_t)s) << 16;
  return v.f;
}
__device__ __forceinline__ float fast_tanh(float xx) {
  float x = fminf(8.f, fmaxf(-8.f, xx));
  float e = __expf(2.f * x);
  return (e - 1.f) * __builtin_amdgcn_rcpf(e + 1.f);
}
__device__ __forceinline__ void nt_st4(float* p, f32x4 v) {
  __builtin_nontemporal_store(v, (f32x4*)p);
}
__device__ __forceinline__ f32x4 nt_ld4(const float* p) {
  return __builtin_nontemporal_load((const f32x4*)p);
}

struct PrepPtrs {
  const float *w1i, *w1h, *w1o, *w2i, *w2h, *w2o, *w3i, *w3h, *w3o;
  const float *b1i, *b1h, *b2i, *b2h, *b3i, *b3h, *bo1, *bo2, *bo3, *wfc, *bfc;
};

// Pack W[n][k] fragments: frag(kt,nt): elem(lane,e) = W[nt*16+(lane&15)][kt*32+(lane>>4)*8+e]
__global__ void prep_kernel(PrepPtrs pp, short* __restrict__ wpk, float* __restrict__ wmisc) {
  const float* P[9] = {pp.w1i, pp.w1h, pp.w1o, pp.w2i, pp.w2h, pp.w2o, pp.w3i, pp.w3h, pp.w3o};
  const int LD_[9] = {64, 256, 256, 64, 256, 256, 130, 256, 256};
  const int C0_[9] = {0, 0, 0, 0, 0, 0, 2, 0, 0};
  const int NT_[9] = {16, 16, 4, 16, 16, 4, 16, 16, 4};
  const int DO_[10] = {0, 16384, 81920, 98304, 114688, 180224, 196608, 229376, 294912, 311296};
  int stride = gridDim.x * blockDim.x;
  for (int g = blockIdx.x * blockDim.x + threadIdx.x; g < 311296; g += stride) {
    int m = 0;
    while (g >= DO_[m + 1]) ++m;
    int p = g - DO_[m];
    int NT = NT_[m];
    int frag = p >> 9, lane = (p >> 3) & 63, e = p & 7;
    int kt = frag / NT, nt = frag - kt * NT;
    int row = nt * 16 + (lane & 15);
    int col = kt * 32 + ((lane >> 4) << 3) + e;
    wpk[g] = f2bf(P[m][(size_t)row * LD_[m] + C0_[m] + col]);
  }
  for (int i = blockIdx.x * blockDim.x + threadIdx.x; i < 1602; i += stride) {
    float v;
    if      (i < 256)  v = pp.b1i[i]         + pp.b1h[i];
    else if (i < 512)  v = pp.b2i[i - 256]   + pp.b2h[i - 256];
    else if (i < 768)  v = pp.b3i[i - 512]   + pp.b3h[i - 512];
    else if (i < 832)  v = pp.bo1[i - 768];
    else if (i < 896)  v = pp.bo2[i - 832];
    else if (i < 960)  v = pp.bo3[i - 896];
    else if (i < 1088) v = pp.wfc[i - 960];
    else if (i < 1090) v = pp.bfc[i - 1088];
    else if (i < 1346) v = pp.w3i[(size_t)(i - 1090) * 130];
    else               v = pp.w3i[(size_t)(i - 1346) * 130 + 1];
    wmisc[i] = v;
  }
}

__launch_bounds__(256, 2)
__global__ void rnn_main(const float* __restrict__ x, const float* __restrict__ cue,
                         const float* __restrict__ hc1, const float* __restrict__ hc2,
                         const float* __restrict__ hc3, const float* __restrict__ hc4,
                         const short* __restrict__ wpk, const float* __restrict__ wmisc,
                         float* __restrict__ out) {
  // 32-row tile, 4 waves. h LDS: element (r,c) at [r*256 + (c ^ ((r&7)<<3))]
  __shared__ __align__(16) short h1s[32 * 256];
  __shared__ __align__(16) short h2s[32 * 256];
  __shared__ __align__(16) short h3s[32 * 256];
  __shared__ __align__(16) short o12s[32 * 128];   // o1 cols 0..63, o2 cols 64..127
  __shared__ __align__(16) float ofl[32 * 72];     // padded f32
  __shared__ float cue0[32], cue1[32];
  __shared__ __align__(16) float misc[1604];

  const int tid = threadIdx.x;
  const int wv = tid >> 6;          // 0..3
  const int lane = tid & 63;
  const int lr = lane & 15;
  const int lq = lane >> 4;
  const int swz = (lr & 7) << 3;
  const int r0 = blockIdx.x * 32;

  float* out_ys  = out;
  float* out_h1  = out + 524288;
  float* out_h2  = out + 4718592;
  float* out_h3  = out + 8912896;
  float* out_h4  = out + 13107200;
  float* out_o1s = out + 17301504;
  float* out_o2s = out + 34078720;
  float* out_cue = out + 50855936;
  float* out_f1  = out + 51380224;
  float* out_f2  = out + 118489088;
  float* out_of  = out + 185597952;

  for (int i = tid; i < 1602; i += 256) misc[i] = wmisc[i];
  if (tid < 32) {
    float cv = cue[r0 + tid];
    cue0[tid] = cv * 10.f;
    cue1[tid] = 10.f * fabsf(cv - 1.f);
  }
  // stage initial h (f32 -> bf16, swizzled) + h4 passthrough
  for (int i = tid; i < 2048; i += 256) {
    int r = i >> 6, c0 = (i & 63) << 2;
    int li = r * 256 + (c0 ^ ((r & 7) << 3));
    size_t g = (size_t)(r0 + r) * 256 + c0;
    f32x4 v1 = __builtin_nontemporal_load((const f32x4*)(hc1 + g));
    f32x4 v2 = __builtin_nontemporal_load((const f32x4*)(hc2 + g));
    f32x4 v3 = __builtin_nontemporal_load((const f32x4*)(hc3 + g));
    f32x4 v4 = __builtin_nontemporal_load((const f32x4*)(hc4 + g));
    *(s16x4*)&h1s[li] = (s16x4){f2bf(v1.x), f2bf(v1.y), f2bf(v1.z), f2bf(v1.w)};
    *(s16x4*)&h2s[li] = (s16x4){f2bf(v2.x), f2bf(v2.y), f2bf(v2.z), f2bf(v2.w)};
    *(s16x4*)&h3s[li] = (s16x4){f2bf(v3.x), f2bf(v3.y), f2bf(v3.z), f2bf(v3.w)};
    nt_st4(out_h4 + g, v4);
  }
  __syncthreads();

  const short* Wp1i  = wpk;
  const short* Wp1h  = wpk + 16384;
  const short* Wp1o  = wpk + 81920;
  const short* Wp2i  = wpk + 98304;
  const short* Wp2h  = wpk + 114688;
  const short* Wp2o  = wpk + 180224;
  const short* Wp3ab = wpk + 196608;
  const short* Wp3h  = wpk + 229376;
  const short* Wp3o  = wpk + 294912;
  const float* bh1v = misc;
  const float* bh2v = misc + 256;
  const float* bh3v = misc + 512;
  const float* bo1v = misc + 768;
  const float* bo2v = misc + 832;
  const float* bofv = misc + 896;
  const float* wfcv = misc + 960;
  const float* bfcv = misc + 1088;
  const float* w3c0 = misc + 1090;
  const float* w3c1 = misc + 1346;

  for (int t = 0; t < TT; ++t) {
    // ---------- Phase A: h1new/h2new; wave owns n-tiles {4wv..4wv+3}; rt=2
    f32x4 acc1[2][4], acc2[2][4];
    #pragma unroll
    for (int j = 0; j < 4; ++j) {
      int nb = (4 * wv + j) * 16 + lq * 4;
      f32x4 b1 = *(const f32x4*)(bh1v + nb);
      f32x4 b2 = *(const f32x4*)(bh2v + nb);
      #pragma unroll
      for (int rt = 0; rt < 2; ++rt) { acc1[rt][j] = b1; acc2[rt][j] = b2; }
    }
    #pragma unroll
    for (int kt = 0; kt < 2; ++kt) {   // x part, K=64
      s16x8 xbk[2];
      #pragma unroll
      for (int rt = 0; rt < 2; ++rt) {
        const float* px = x + ((size_t)t * BN + r0 + rt * 16 + lr) * 64 + kt * 32 + lq * 8;
        f32x4 a0 = nt_ld4(px);
        f32x4 a1 = nt_ld4(px + 4);
        xbk[rt] = (s16x8){f2bf(a0.x), f2bf(a0.y), f2bf(a0.z), f2bf(a0.w),
                          f2bf(a1.x), f2bf(a1.y), f2bf(a1.z), f2bf(a1.w)};
      }
      #pragma unroll
      for (int j = 0; j < 4; ++j) {
        s16x8 a1w = *(const s16x8*)(Wp1i + ((size_t)(kt * 16 + 4 * wv + j) * 64 + lane) * 8);
        s16x8 a2w = *(const s16x8*)(Wp2i + ((size_t)(kt * 16 + 4 * wv + j) * 64 + lane) * 8);
        #pragma unroll
        for (int rt = 0; rt < 2; ++rt) {
          acc1[rt][j] = MFMA(a1w, xbk[rt], acc1[rt][j]);
          acc2[rt][j] = MFMA(a2w, xbk[rt], acc2[rt][j]);
        }
      }
    }
    #pragma unroll
    for (int kt = 0; kt < 8; ++kt) {   // recurrent, K=256
      s16x8 w1f[4], w2f[4];
      #pragma unroll
      for (int j = 0; j < 4; ++j) {
        w1f[j] = *(const s16x8*)(Wp1h + ((size_t)(kt * 16 + 4 * wv + j) * 64 + lane) * 8);
        w2f[j] = *(const s16x8*)(Wp2h + ((size_t)(kt * 16 + 4 * wv + j) * 64 + lane) * 8);
      }
      s16x8 hb1[2], hb2[2];
      #pragma unroll
      for (int rt = 0; rt < 2; ++rt) {
        int ad = (rt * 16 + lr) * 256 + ((kt * 32 + lq * 8) ^ swz);
        hb1[rt] = *(const s16x8*)&h1s[ad];
        hb2[rt] = *(const s16x8*)&h2s[ad];
      }
      #pragma unroll
      for (int j = 0; j < 4; ++j) {
        #pragma unroll
        for (int rt = 0; rt < 2; ++rt) {
          acc1[rt][j] = MFMA(w1f[j], hb1[rt], acc1[rt][j]);
          acc2[rt][j] = MFMA(w2f[j], hb2[rt], acc2[rt][j]);
        }
      }
    }
    __syncthreads();   // all done reading old h1/h2
    #pragma unroll
    for (int j = 0; j < 4; ++j) {
      int cb = (4 * wv + j) * 16 + lq * 4;
      #pragma unroll
      for (int rt = 0; rt < 2; ++rt) {
        int ad = (rt * 16 + lr) * 256 + (cb ^ swz);
        *(s16x4*)&h1s[ad] = (s16x4){f2bf(fast_tanh(acc1[rt][j][0])), f2bf(fast_tanh(acc1[rt][j][1])),
                                    f2bf(fast_tanh(acc1[rt][j][2])), f2bf(fast_tanh(acc1[rt][j][3]))};
        *(s16x4*)&h2s[ad] = (s16x4){f2bf(fast_tanh(acc2[rt][j][0])), f2bf(fast_tanh(acc2[rt][j][1])),
                                    f2bf(fast_tanh(acc2[rt][j][2])), f2bf(fast_tanh(acc2[rt][j][3]))};
      }
    }
    __syncthreads();

    // ---------- Phase B: waves 0-1 -> o1, waves 2-3 -> o2 (2 n-tiles each)
    {
      int cell = wv >> 1, wj = wv & 1;
      const short* hs = cell ? h2s : h1s;
      const short* Wo = cell ? Wp2o : Wp1o;
      const float* bo = cell ? bo2v : bo1v;
      f32x4 acc[2][2];
      #pragma unroll
      for (int j = 0; j < 2; ++j) {
        int nb = (2 * wj + j) * 16 + lq * 4;
        f32x4 bb = *(const f32x4*)(bo + nb);
        #pragma unroll
        for (int rt = 0; rt < 2; ++rt) acc[rt][j] = bb;
      }
      #pragma unroll
      for (int kt = 0; kt < 8; ++kt) {
        s16x8 aw0 = *(const s16x8*)(Wo + ((size_t)(kt * 4 + 2 * wj) * 64 + lane) * 8);
        s16x8 aw1 = *(const s16x8*)(Wo + ((size_t)(kt * 4 + 2 * wj + 1) * 64 + lane) * 8);
        #pragma unroll
        for (int rt = 0; rt < 2; ++rt) {
          s16x8 hb = *(const s16x8*)&hs[(rt * 16 + lr) * 256 + ((kt * 32 + lq * 8) ^ swz)];
          acc[rt][0] = MFMA(aw0, hb, acc[rt][0]);
          acc[rt][1] = MFMA(aw1, hb, acc[rt][1]);
        }
      }
      #pragma unroll
      for (int j = 0; j < 2; ++j) {
        int cb = cell * 64 + (2 * wj + j) * 16 + lq * 4;
        #pragma unroll
        for (int rt = 0; rt < 2; ++rt) {
          *(s16x4*)&o12s[(rt * 16 + lr) * 128 + (cb ^ swz)] =
              (s16x4){f2bf(fast_tanh(acc[rt][j][0])), f2bf(fast_tanh(acc[rt][j][1])),
                      f2bf(fast_tanh(acc[rt][j][2])), f2bf(fast_tanh(acc[rt][j][3]))};
        }
      }
    }
    __syncthreads();

    // ---------- Phase C: h3new (4 n-tiles per wave)
    {
      f32x4 acc3[2][4];
      #pragma unroll
      for (int j = 0; j < 4; ++j) {
        int nb = (4 * wv + j) * 16 + lq * 4;
        f32x4 bb  = *(const f32x4*)(bh3v + nb);
        f32x4 c0w = *(const f32x4*)(w3c0 + nb);
        f32x4 c1w = *(const f32x4*)(w3c1 + nb);
        #pragma unroll
        for (int rt = 0; rt < 2; ++rt) {
          float cz = cue0[rt * 16 + lr], co = cue1[rt * 16 + lr];
          acc3[rt][j] = bb + cz * c0w + co * c1w;
        }
      }
      #pragma unroll
      for (int kt = 0; kt < 4; ++kt) {   // [o1|o2], K=128
        s16x8 ob[2];
        #pragma unroll
        for (int rt = 0; rt < 2; ++rt)
          ob[rt] = *(const s16x8*)&o12s[(rt * 16 + lr) * 128 + ((kt * 32 + lq * 8) ^ swz)];
        #pragma unroll
        for (int j = 0; j < 4; ++j) {
          s16x8 aw = *(const s16x8*)(Wp3ab + ((size_t)(kt * 16 + 4 * wv + j) * 64 + lane) * 8);
          #pragma unroll
          for (int rt = 0; rt < 2; ++rt) acc3[rt][j] = MFMA(aw, ob[rt], acc3[rt][j]);
        }
      }
      #pragma unroll
      for (int kt = 0; kt < 8; ++kt) {   // recurrent, K=256
        s16x8 hb[2];
        #pragma unroll
        for (int rt = 0; rt < 2; ++rt)
          hb[rt] = *(const s16x8*)&h3s[(rt * 16 + lr) * 256 + ((kt * 32 + lq * 8) ^ swz)];
        #pragma unroll
        for (int j = 0; j < 4; ++j) {
          s16x8 aw = *(const s16x8*)(Wp3h + ((size_t)(kt * 16 + 4 * wv + j) * 64 + lane) * 8);
          #pragma unroll
          for (int rt = 0; rt < 2; ++rt) acc3[rt][j] = MFMA(aw, hb[rt], acc3[rt][j]);
        }
      }
      __syncthreads();   // done reading old h3
      #pragma unroll
      for (int j = 0; j < 4; ++j) {
        int cb = (4 * wv + j) * 16 + lq * 4;
        #pragma unroll
        for (int rt = 0; rt < 2; ++rt) {
          *(s16x4*)&h3s[(rt * 16 + lr) * 256 + (cb ^ swz)] =
              (s16x4){f2bf(fast_tanh(acc3[rt][j][0])), f2bf(fast_tanh(acc3[rt][j][1])),
                      f2bf(fast_tanh(acc3[rt][j][2])), f2bf(fast_tanh(acc3[rt][j][3]))};
        }
      }
      __syncthreads();
    }

    // ---------- Phase D: waves 0-1 compute of; wave 2 stores o1s, wave 3 stores o2s
    if (wv < 2) {
      f32x4 acc[2][2];
      #pragma unroll
      for (int j = 0; j < 2; ++j) {
        int nb = (2 * wv + j) * 16 + lq * 4;
        f32x4 bb = *(const f32x4*)(bofv + nb);
        #pragma unroll
        for (int rt = 0; rt < 2; ++rt) acc[rt][j] = bb;
      }
      #pragma unroll
      for (int kt = 0; kt < 8; ++kt) {
        s16x8 aw0 = *(const s16x8*)(Wp3o + ((size_t)(kt * 4 + 2 * wv) * 64 + lane) * 8);
        s16x8 aw1 = *(const s16x8*)(Wp3o + ((size_t)(kt * 4 + 2 * wv + 1) * 64 + lane) * 8);
        #pragma unroll
        for (int rt = 0; rt < 2; ++rt) {
          s16x8 hb = *(const s16x8*)&h3s[(rt * 16 + lr) * 256 + ((kt * 32 + lq * 8) ^ swz)];
          acc[rt][0] = MFMA(aw0, hb, acc[rt][0]);
          acc[rt][1] = MFMA(aw1, hb, acc[rt][1]);
        }
      }
      #pragma unroll
      for (int j = 0; j < 2; ++j) {
        int nb = (2 * wv + j) * 16 + lq * 4;
        #pragma unroll
        for (int rt = 0; rt < 2; ++rt) {
          f32x4 v = (f32x4){fmaxf(0.f, acc[rt][j][0]), fmaxf(0.f, acc[rt][j][1]),
                            fmaxf(0.f, acc[rt][j][2]), fmaxf(0.f, acc[rt][j][3])};
          *(f32x4*)&ofl[(rt * 16 + lr) * 72 + nb] = v;
        }
      }
    } else {
      // wave 2 -> o1s, wave 3 -> o2s; 2048 f32 each = 512 f32x4 / 64 lanes
      size_t ob = ((size_t)t * BN + r0) * 64;
      float* targ = (wv == 2) ? out_o1s : out_o2s;
      int coff = (wv == 2) ? 0 : 64;
      #pragma unroll
      for (int s = 0; s < 8; ++s) {
        int f = (s * 64 + lane) * 4;
        int r = f >> 6, c = f & 63;
        s16x4 v = *(const s16x4*)&o12s[r * 128 + ((c + coff) ^ ((r & 7) << 3))];
        nt_st4(targ + ob + f, (f32x4){bf2f(v[0]), bf2f(v[1]), bf2f(v[2]), bf2f(v[3])});
      }
    }
    __syncthreads();

    // ---------- Phase E: of store + y + cue_arr + feed zero-fill (NT)
    {
      size_t ob = ((size_t)t * BN + r0) * 64;
      #pragma unroll
      for (int s = 0; s < 2; ++s) {       // of: 512 f32x4 over 256 threads
        int v = s * 256 + tid;
        int r = v >> 4, c0 = (v & 15) << 2;
        nt_st4(out_of + ob + r * 64 + c0, *(const f32x4*)&ofl[r * 72 + c0]);
      }
      if (tid < 64) {
        int rr = tid >> 1, jj = tid & 1;
        const f32x4* wr4 = (const f32x4*)(wfcv + jj * 64);
        const f32x4* or4 = (const f32x4*)&ofl[rr * 72];
        f32x4 sv = (f32x4){0.f, 0.f, 0.f, 0.f};
        #pragma unroll
        for (int kk = 0; kk < 16; ++kk) sv += or4[kk] * wr4[kk];
        float s = bfcv[jj] + sv[0] + sv[1] + sv[2] + sv[3];
        size_t yi = ((size_t)t * BN + r0 + rr) * 2 + jj;
        __builtin_nontemporal_store(s, out_ys + yi);
        __builtin_nontemporal_store(jj ? cue1[rr] : cue0[rr], out_cue + yi);
      }
      size_t fb = ((size_t)t * BN + r0) * 256;   // 8192 f32 per feed array
      f32x4 z = (f32x4){0.f, 0.f, 0.f, 0.f};
      #pragma unroll
      for (int s = 0; s < 8; ++s) {
        nt_st4(out_f1 + fb + (size_t)(s * 256 + tid) * 4, z);
        nt_st4(out_f2 + fb + (size_t)(s * 256 + tid) * 4, z);
      }
    }
    // no trailing barrier: ofl/o12s next written >=2 barriers into step t+1
  }

  // final h states
  for (int i = tid; i < 2048; i += 256) {
    int r = i >> 6, c0 = (i & 63) << 2;
    int li = r * 256 + (c0 ^ ((r & 7) << 3));
    size_t g = (size_t)(r0 + r) * 256 + c0;
    s16x4 s1 = *(const s16x4*)&h1s[li];
    s16x4 s2 = *(const s16x4*)&h2s[li];
    s16x4 s3 = *(const s16x4*)&h3s[li];
    nt_st4(out_h1 + g, (f32x4){bf2f(s1[0]), bf2f(s1[1]), bf2f(s1[2]), bf2f(s1[3])});
    nt_st4(out_h2 + g, (f32x4){bf2f(s2[0]), bf2f(s2[1]), bf2f(s2[2]), bf2f(s2[3])});
    nt_st4(out_h3 + g, (f32x4){bf2f(s3[0]), bf2f(s3[1]), bf2f(s3[2]), bf2f(s3[3])});
  }
}

extern "C" void kernel_launch(void* const* d_in, const int* in_sizes, int n_in,
                              void* d_out, int out_size, void* d_ws, size_t ws_size,
                              hipStream_t stream) {
  const float* x   = (const float*)d_in[0];
  const float* cue = (const float*)d_in[1];
  const float* hc1 = (const float*)d_in[2];
  const float* hc2 = (const float*)d_in[3];
  const float* hc3 = (const float*)d_in[4];
  const float* hc4 = (const float*)d_in[5];
  PrepPtrs pp;
  pp.w1i = (const float*)d_in[6];  pp.b1i = (const float*)d_in[7];
  pp.w1h = (const float*)d_in[8];  pp.b1h = (const float*)d_in[9];
  pp.w1o = (const float*)d_in[10]; pp.bo1 = (const float*)d_in[11];
  pp.w2i = (const float*)d_in[12]; pp.b2i = (const float*)d_in[13];
  pp.w2h = (const float*)d_in[14]; pp.b2h = (const float*)d_in[15];
  pp.w2o = (const float*)d_in[16]; pp.bo2 = (const float*)d_in[17];
  pp.w3i = (const float*)d_in[18]; pp.b3i = (const float*)d_in[19];
  pp.w3h = (const float*)d_in[20]; pp.b3h = (const float*)d_in[21];
  pp.w3o = (const float*)d_in[22]; pp.bo3 = (const float*)d_in[23];
  pp.wfc = (const float*)d_in[24]; pp.bfc = (const float*)d_in[25];

  short* wpk   = (short*)d_ws;                       // 311296 bf16 = 622592 B
  float* wmisc = (float*)((char*)d_ws + 622592);     // 1602 f32

  prep_kernel<<<64, 256, 0, stream>>>(pp, wpk, wmisc);
  rnn_main<<<512, 256, 0, stream>>>(x, cue, hc1, hc2, hc3, hc4, wpk, wmisc, (float*)d_out);
}

// Round 11
// 839.207 us; speedup vs baseline: 1.4429x; 1.4429x over previous
//
#include <hip/hip_runtime.h>
#include <stdint.h>
#include <stddef.h>

// RNN_arch_2_final: 3-cell stacked RNN, T=16, B=16384, hidden 256.
// R11: R8 geometry (512thr/64-row/256WG). Key change: in-loop barriers are
// raw `s_waitcnt lgkmcnt(0); s_barrier` (NOT __syncthreads) so the compiler's
// vmcnt(0) drain is gone -> NT stores ack in background, weight prefetches
// survive barriers. Cross-barrier prefetch of Wo/W3ab/W3o at acc-dead points.

#define BN 16384
#define TT 16

typedef short s16x8 __attribute__((ext_vector_type(8)));
typedef short s16x4 __attribute__((ext_vector_type(4)));
typedef float f32x4 __attribute__((ext_vector_type(4)));

#define MFMA(a, b, c) __builtin_amdgcn_mfma_f32_16x16x32_bf16((a), (b), (c), 0, 0, 0)
// LDS-ordering barrier WITHOUT vmcnt drain (global loads/stores stay in flight).
// Safe: only LDS carries cross-wave hazards in the t-loop; global reads are
// read-only (weights/x) and global stores have no in-kernel readers.
#define BAR() asm volatile("s_waitcnt lgkmcnt(0)\n\ts_barrier" ::: "memory")

__device__ __forceinline__ short f2bf(float f) {
  union { float f; uint32_t u; } v; v.f = f;
  uint32_t u = v.u;
  u += 0x7FFFu + ((u >> 16) & 1u);   // RNE
  return (short)(u >> 16);
}
__device__ __forceinline__ float bf2f(short s) {
  union { uint32_t u; float f; } v; v.u = ((uint32_t)(uint16_t)s) << 16;
  return v.f;
}
__device__ __forceinline__ float fast_tanh(float xx) {
  float x = fminf(8.f, fmaxf(-8.f, xx));
  float e = __expf(2.f * x);
  return (e - 1.f) * __builtin_amdgcn_rcpf(e + 1.f);
}
__device__ __forceinline__ void nt_st4(float* p, f32x4 v) {
  __builtin_nontemporal_store(v, (f32x4*)p);
}
__device__ __forceinline__ f32x4 nt_ld4(const float* p) {
  return __builtin_nontemporal_load((const f32x4*)p);
}

struct PrepPtrs {
  const float *w1i, *w1h, *w1o, *w2i, *w2h, *w2o, *w3i, *w3h, *w3o;
  const float *b1i, *b1h, *b2i, *b2h, *b3i, *b3h, *bo1, *bo2, *bo3, *wfc, *bfc;
};

// Pack W[n][k] fragments: frag(kt,nt): elem(lane,e) = W[nt*16+(lane&15)][kt*32+(lane>>4)*8+e]
__global__ void prep_kernel(PrepPtrs pp, short* __restrict__ wpk, float* __restrict__ wmisc) {
  const float* P[9] = {pp.w1i, pp.w1h, pp.w1o, pp.w2i, pp.w2h, pp.w2o, pp.w3i, pp.w3h, pp.w3o};
  const int LD_[9] = {64, 256, 256, 64, 256, 256, 130, 256, 256};
  const int C0_[9] = {0, 0, 0, 0, 0, 0, 2, 0, 0};
  const int NT_[9] = {16, 16, 4, 16, 16, 4, 16, 16, 4};
  const int DO_[10] = {0, 16384, 81920, 98304, 114688, 180224, 196608, 229376, 294912, 311296};
  int stride = gridDim.x * blockDim.x;
  for (int g = blockIdx.x * blockDim.x + threadIdx.x; g < 311296; g += stride) {
    int m = 0;
    while (g >= DO_[m + 1]) ++m;
    int p = g - DO_[m];
    int NT = NT_[m];
    int frag = p >> 9, lane = (p >> 3) & 63, e = p & 7;
    int kt = frag / NT, nt = frag - kt * NT;
    int row = nt * 16 + (lane & 15);
    int col = kt * 32 + ((lane >> 4) << 3) + e;
    wpk[g] = f2bf(P[m][(size_t)row * LD_[m] + C0_[m] + col]);
  }
  for (int i = blockIdx.x * blockDim.x + threadIdx.x; i < 1602; i += stride) {
    float v;
    if      (i < 256)  v = pp.b1i[i]         + pp.b1h[i];
    else if (i < 512)  v = pp.b2i[i - 256]   + pp.b2h[i - 256];
    else if (i < 768)  v = pp.b3i[i - 512]   + pp.b3h[i - 512];
    else if (i < 832)  v = pp.bo1[i - 768];
    else if (i < 896)  v = pp.bo2[i - 832];
    else if (i < 960)  v = pp.bo3[i - 896];
    else if (i < 1088) v = pp.wfc[i - 960];
    else if (i < 1090) v = pp.bfc[i - 1088];
    else if (i < 1346) v = pp.w3i[(size_t)(i - 1090) * 130];
    else               v = pp.w3i[(size_t)(i - 1346) * 130 + 1];
    wmisc[i] = v;
  }
}

__launch_bounds__(512, 2)
__global__ void rnn_main(const float* __restrict__ x, const float* __restrict__ cue,
                         const float* __restrict__ hc1, const float* __restrict__ hc2,
                         const float* __restrict__ hc3, const float* __restrict__ hc4,
                         const short* __restrict__ wpk, const float* __restrict__ wmisc,
                         float* __restrict__ out) {
  // h LDS: element (r,c) at [r*256 + (c ^ ((r&7)<<3))]  (16-B granule XOR swizzle)
  __shared__ __align__(16) short h1s[64 * 256];
  __shared__ __align__(16) short h2s[64 * 256];
  __shared__ __align__(16) short h3s[64 * 256];
  __shared__ __align__(16) short o12s[64 * 128];   // o1 cols 0..63, o2 cols 64..127
  __shared__ __align__(16) float ofl[64 * 72];     // padded f32
  __shared__ float cue0[64], cue1[64];
  __shared__ __align__(16) float misc[1604];

  const int tid = threadIdx.x;
  const int wv = tid >> 6;          // 0..7
  const int lane = tid & 63;
  const int lr = lane & 15;
  const int lq = lane >> 4;
  const int swz = (lr & 7) << 3;
  const int r0 = blockIdx.x * 64;

  float* out_ys  = out;
  float* out_h1  = out + 524288;
  float* out_h2  = out + 4718592;
  float* out_h3  = out + 8912896;
  float* out_h4  = out + 13107200;
  float* out_o1s = out + 17301504;
  float* out_o2s = out + 34078720;
  float* out_cue = out + 50855936;
  float* out_f1  = out + 51380224;
  float* out_f2  = out + 118489088;
  float* out_of  = out + 185597952;

  for (int i = tid; i < 1602; i += 512) misc[i] = wmisc[i];
  if (tid < 64) {
    float cv = cue[r0 + tid];
    cue0[tid] = cv * 10.f;
    cue1[tid] = 10.f * fabsf(cv - 1.f);
  }
  // stage initial h (f32 -> bf16, swizzled) + h4 passthrough
  for (int i = tid; i < 4096; i += 512) {
    int r = i >> 6, c0 = (i & 63) << 2;
    int li = r * 256 + (c0 ^ ((r & 7) << 3));
    size_t g = (size_t)(r0 + r) * 256 + c0;
    f32x4 v1 = __builtin_nontemporal_load((const f32x4*)(hc1 + g));
    f32x4 v2 = __builtin_nontemporal_load((const f32x4*)(hc2 + g));
    f32x4 v3 = __builtin_nontemporal_load((const f32x4*)(hc3 + g));
    f32x4 v4 = __builtin_nontemporal_load((const f32x4*)(hc4 + g));
    *(s16x4*)&h1s[li] = (s16x4){f2bf(v1.x), f2bf(v1.y), f2bf(v1.z), f2bf(v1.w)};
    *(s16x4*)&h2s[li] = (s16x4){f2bf(v2.x), f2bf(v2.y), f2bf(v2.z), f2bf(v2.w)};
    *(s16x4*)&h3s[li] = (s16x4){f2bf(v3.x), f2bf(v3.y), f2bf(v3.z), f2bf(v3.w)};
    nt_st4(out_h4 + g, v4);
  }
  __syncthreads();

  const short* Wp1i  = wpk;
  const short* Wp1h  = wpk + 16384;
  const short* Wp1o  = wpk + 81920;
  const short* Wp2i  = wpk + 98304;
  const short* Wp2h  = wpk + 114688;
  const short* Wp2o  = wpk + 180224;
  const short* Wp3ab = wpk + 196608;
  const short* Wp3h  = wpk + 229376;
  const short* Wp3o  = wpk + 294912;
  const float* bh1v = misc;
  const float* bh2v = misc + 256;
  const float* bh3v = misc + 512;
  const float* bo1v = misc + 768;
  const float* bo2v = misc + 832;
  const float* bofv = misc + 896;
  const float* wfcv = misc + 960;
  const float* bfcv = misc + 1088;
  const float* w3c0 = misc + 1090;
  const float* w3c1 = misc + 1346;

  for (int t = 0; t < TT; ++t) {
    // ---------- Phase A: h1new/h2new; acc[rt][j], lane holds 4 consecutive n
    f32x4 acc1[4][2], acc2[4][2];
    #pragma unroll
    for (int j = 0; j < 2; ++j) {
      int nb = (2 * wv + j) * 16 + lq * 4;
      f32x4 b1 = *(const f32x4*)(bh1v + nb);
      f32x4 b2 = *(const f32x4*)(bh2v + nb);
      #pragma unroll
      for (int rt = 0; rt < 4; ++rt) { acc1[rt][j] = b1; acc2[rt][j] = b2; }
    }
    // x part
    #pragma unroll
    for (int kt = 0; kt < 2; ++kt) {
      s16x8 xbk[4];
      #pragma unroll
      for (int rt = 0; rt < 4; ++rt) {
        const float* px = x + ((size_t)t * BN + r0 + rt * 16 + lr) * 64 + kt * 32 + lq * 8;
        f32x4 a0 = nt_ld4(px);
        f32x4 a1 = nt_ld4(px + 4);
        xbk[rt] = (s16x8){f2bf(a0.x), f2bf(a0.y), f2bf(a0.z), f2bf(a0.w),
                          f2bf(a1.x), f2bf(a1.y), f2bf(a1.z), f2bf(a1.w)};
      }
      s16x8 a1w0 = *(const s16x8*)(Wp1i + ((size_t)(kt * 16 + 2 * wv) * 64 + lane) * 8);
      s16x8 a1w1 = *(const s16x8*)(Wp1i + ((size_t)(kt * 16 + 2 * wv + 1) * 64 + lane) * 8);
      s16x8 a2w0 = *(const s16x8*)(Wp2i + ((size_t)(kt * 16 + 2 * wv) * 64 + lane) * 8);
      s16x8 a2w1 = *(const s16x8*)(Wp2i + ((size_t)(kt * 16 + 2 * wv + 1) * 64 + lane) * 8);
      #pragma unroll
      for (int rt = 0; rt < 4; ++rt) {
        acc1[rt][0] = MFMA(a1w0, xbk[rt], acc1[rt][0]);
        acc1[rt][1] = MFMA(a1w1, xbk[rt], acc1[rt][1]);
        acc2[rt][0] = MFMA(a2w0, xbk[rt], acc2[rt][0]);
        acc2[rt][1] = MFMA(a2w1, xbk[rt], acc2[rt][1]);
      }
    }
    // recurrent
    #pragma unroll
    for (int kt = 0; kt < 8; ++kt) {
      s16x8 w1_0 = *(const s16x8*)(Wp1h + ((size_t)(kt * 16 + 2 * wv) * 64 + lane) * 8);
      s16x8 w1_1 = *(const s16x8*)(Wp1h + ((size_t)(kt * 16 + 2 * wv + 1) * 64 + lane) * 8);
      s16x8 w2_0 = *(const s16x8*)(Wp2h + ((size_t)(kt * 16 + 2 * wv) * 64 + lane) * 8);
      s16x8 w2_1 = *(const s16x8*)(Wp2h + ((size_t)(kt * 16 + 2 * wv + 1) * 64 + lane) * 8);
      s16x8 hb1[4], hb2[4];
      #pragma unroll
      for (int rt = 0; rt < 4; ++rt) {
        int ad = (rt * 16 + lr) * 256 + ((kt * 32 + lq * 8) ^ swz);
        hb1[rt] = *(const s16x8*)&h1s[ad];
        hb2[rt] = *(const s16x8*)&h2s[ad];
      }
      #pragma unroll
      for (int rt = 0; rt < 4; ++rt) {
        acc1[rt][0] = MFMA(w1_0, hb1[rt], acc1[rt][0]);
        acc1[rt][1] = MFMA(w1_1, hb1[rt], acc1[rt][1]);
        acc2[rt][0] = MFMA(w2_0, hb2[rt], acc2[rt][0]);
        acc2[rt][1] = MFMA(w2_1, hb2[rt], acc2[rt][1]);
      }
    }
    BAR();   // all done reading old h1/h2  (no vmcnt drain)
    // h-write epilogue; prefetch phase-B weights (accs die here, pressure low)
    s16x8 wo_pf[8];
    {
      int cell = wv >> 2, w4 = wv & 3;
      const short* Wo = cell ? Wp2o : Wp1o;
      #pragma unroll
      for (int kt = 0; kt < 8; ++kt)
        wo_pf[kt] = *(const s16x8*)(Wo + ((size_t)(kt * 4 + w4) * 64 + lane) * 8);
    }
    #pragma unroll
    for (int j = 0; j < 2; ++j) {
      int cb = (2 * wv + j) * 16 + lq * 4;
      #pragma unroll
      for (int rt = 0; rt < 4; ++rt) {
        int ad = (rt * 16 + lr) * 256 + (cb ^ swz);
        *(s16x4*)&h1s[ad] = (s16x4){f2bf(fast_tanh(acc1[rt][j][0])), f2bf(fast_tanh(acc1[rt][j][1])),
                                    f2bf(fast_tanh(acc1[rt][j][2])), f2bf(fast_tanh(acc1[rt][j][3]))};
        *(s16x4*)&h2s[ad] = (s16x4){f2bf(fast_tanh(acc2[rt][j][0])), f2bf(fast_tanh(acc2[rt][j][1])),
                                    f2bf(fast_tanh(acc2[rt][j][2])), f2bf(fast_tanh(acc2[rt][j][3]))};
      }
    }
    BAR();

    // ---------- Phase B: o1 (waves 0-3) / o2 (waves 4-7) using prefetched Wo
    s16x8 w3ab_pf[4][2];
    {
      int cell = wv >> 2, w4 = wv & 3;
      const short* hs = cell ? h2s : h1s;
      const float* bo = cell ? bo2v : bo1v;
      int nb = w4 * 16 + lq * 4;
      f32x4 bb = *(const f32x4*)(bo + nb);
      f32x4 acc[4];
      #pragma unroll
      for (int rt = 0; rt < 4; ++rt) acc[rt] = bb;
      #pragma unroll
      for (int kt = 0; kt < 8; ++kt) {
        #pragma unroll
        for (int rt = 0; rt < 4; ++rt) {
          s16x8 hb = *(const s16x8*)&hs[(rt * 16 + lr) * 256 + ((kt * 32 + lq * 8) ^ swz)];
          acc[rt] = MFMA(wo_pf[kt], hb, acc[rt]);
        }
      }
      // prefetch phase-C W3ab while acc retires
      #pragma unroll
      for (int kt = 0; kt < 4; ++kt) {
        w3ab_pf[kt][0] = *(const s16x8*)(Wp3ab + ((size_t)(kt * 16 + 2 * wv) * 64 + lane) * 8);
        w3ab_pf[kt][1] = *(const s16x8*)(Wp3ab + ((size_t)(kt * 16 + 2 * wv + 1) * 64 + lane) * 8);
      }
      int cb = cell * 64 + nb;
      #pragma unroll
      for (int rt = 0; rt < 4; ++rt) {
        *(s16x4*)&o12s[(rt * 16 + lr) * 128 + (cb ^ swz)] =
            (s16x4){f2bf(fast_tanh(acc[rt][0])), f2bf(fast_tanh(acc[rt][1])),
                    f2bf(fast_tanh(acc[rt][2])), f2bf(fast_tanh(acc[rt][3]))};
      }
    }
    BAR();

    // ---------- Phase C: h3new
    s16x8 w3o_pf[8];
    {
      f32x4 acc3[4][2];
      #pragma unroll
      for (int j = 0; j < 2; ++j) {
        int nb = (2 * wv + j) * 16 + lq * 4;
        f32x4 bb  = *(const f32x4*)(bh3v + nb);
        f32x4 c0w = *(const f32x4*)(w3c0 + nb);
        f32x4 c1w = *(const f32x4*)(w3c1 + nb);
        #pragma unroll
        for (int rt = 0; rt < 4; ++rt) {
          float cz = cue0[rt * 16 + lr], co = cue1[rt * 16 + lr];
          acc3[rt][j] = bb + cz * c0w + co * c1w;
        }
      }
      #pragma unroll
      for (int kt = 0; kt < 4; ++kt) {   // [o1|o2], K=128 (prefetched)
        #pragma unroll
        for (int rt = 0; rt < 4; ++rt) {
          s16x8 ob = *(const s16x8*)&o12s[(rt * 16 + lr) * 128 + ((kt * 32 + lq * 8) ^ swz)];
          acc3[rt][0] = MFMA(w3ab_pf[kt][0], ob, acc3[rt][0]);
          acc3[rt][1] = MFMA(w3ab_pf[kt][1], ob, acc3[rt][1]);
        }
      }
      #pragma unroll
      for (int kt = 0; kt < 8; ++kt) {   // recurrent, K=256 (streamed)
        s16x8 aw0 = *(const s16x8*)(Wp3h + ((size_t)(kt * 16 + 2 * wv) * 64 + lane) * 8);
        s16x8 aw1 = *(const s16x8*)(Wp3h + ((size_t)(kt * 16 + 2 * wv + 1) * 64 + lane) * 8);
        #pragma unroll
        for (int rt = 0; rt < 4; ++rt) {
          s16x8 hb = *(const s16x8*)&h3s[(rt * 16 + lr) * 256 + ((kt * 32 + lq * 8) ^ swz)];
          acc3[rt][0] = MFMA(aw0, hb, acc3[rt][0]);
          acc3[rt][1] = MFMA(aw1, hb, acc3[rt][1]);
        }
      }
      BAR();   // done reading old h3
      // prefetch phase-D W3o (waves 0-3 only) while writing h3
      if (wv < 4) {
        #pragma unroll
        for (int kt = 0; kt < 8; ++kt)
          w3o_pf[kt] = *(const s16x8*)(Wp3o + ((size_t)(kt * 4 + wv) * 64 + lane) * 8);
      }
      #pragma unroll
      for (int j = 0; j < 2; ++j) {
        int cb = (2 * wv + j) * 16 + lq * 4;
        #pragma unroll
        for (int rt = 0; rt < 4; ++rt) {
          *(s16x4*)&h3s[(rt * 16 + lr) * 256 + (cb ^ swz)] =
              (s16x4){f2bf(fast_tanh(acc3[rt][j][0])), f2bf(fast_tanh(acc3[rt][j][1])),
                      f2bf(fast_tanh(acc3[rt][j][2])), f2bf(fast_tanh(acc3[rt][j][3]))};
        }
      }
      BAR();
    }

    // ---------- Phase D: waves 0-3 compute of (prefetched W3o); 4-7 store o1s/o2s
    if (wv < 4) {
      int nb = wv * 16 + lq * 4;
      f32x4 bb = *(const f32x4*)(bofv + nb);
      f32x4 acc[4];
      #pragma unroll
      for (int rt = 0; rt < 4; ++rt) acc[rt] = bb;
      #pragma unroll
      for (int kt = 0; kt < 8; ++kt) {
        #pragma unroll
        for (int rt = 0; rt < 4; ++rt) {
          s16x8 hb = *(const s16x8*)&h3s[(rt * 16 + lr) * 256 + ((kt * 32 + lq * 8) ^ swz)];
          acc[rt] = MFMA(w3o_pf[kt], hb, acc[rt]);
        }
      }
      #pragma unroll
      for (int rt = 0; rt < 4; ++rt) {
        f32x4 v = (f32x4){fmaxf(0.f, acc[rt][0]), fmaxf(0.f, acc[rt][1]),
                          fmaxf(0.f, acc[rt][2]), fmaxf(0.f, acc[rt][3])};
        *(f32x4*)&ofl[(rt * 16 + lr) * 72 + nb] = v;
      }
    } else {
      size_t ob = ((size_t)t * BN + r0) * 64;
      float* targ = (wv < 6) ? out_o1s : out_o2s;
      int coff = (wv < 6) ? 0 : 64;
      int wq = wv & 1;
      #pragma unroll
      for (int s = 0; s < 8; ++s) {
        int f = wq * 2048 + s * 256 + lane * 4;
        int r = f >> 6, c = f & 63;
        s16x4 v = *(const s16x4*)&o12s[r * 128 + ((c + coff) ^ ((r & 7) << 3))];
        nt_st4(targ + ob + f, (f32x4){bf2f(v[0]), bf2f(v[1]), bf2f(v[2]), bf2f(v[3])});
      }
    }
    BAR();

    // ---------- Phase E: of store + y + cue_arr + feed zero-fill (NT)
    {
      size_t ob = ((size_t)t * BN + r0) * 64;
      int r = tid >> 3, c0 = (tid & 7) << 3;
      nt_st4(out_of + ob + r * 64 + c0,     *(const f32x4*)&ofl[r * 72 + c0]);
      nt_st4(out_of + ob + r * 64 + c0 + 4, *(const f32x4*)&ofl[r * 72 + c0 + 4]);
      if (tid < 128) {
        int rr = tid >> 1, jj = tid & 1;
        const f32x4* wr4 = (const f32x4*)(wfcv + jj * 64);
        const f32x4* or4 = (const f32x4*)&ofl[rr * 72];
        f32x4 sv = (f32x4){0.f, 0.f, 0.f, 0.f};
        #pragma unroll
        for (int kk = 0; kk < 16; ++kk) sv += or4[kk] * wr4[kk];
        float s = bfcv[jj] + sv[0] + sv[1] + sv[2] + sv[3];
        size_t yi = ((size_t)t * BN + r0 + rr) * 2 + jj;
        __builtin_nontemporal_store(s, out_ys + yi);
        __builtin_nontemporal_store(jj ? cue1[rr] : cue0[rr], out_cue + yi);
      }
      size_t fb = ((size_t)t * BN + r0) * 256;   // 16384 floats per feed array
      f32x4 z = (f32x4){0.f, 0.f, 0.f, 0.f};
      #pragma unroll
      for (int s = 0; s < 8; ++s) {
        nt_st4(out_f1 + fb + (size_t)(s * 512 + tid) * 4, z);
        nt_st4(out_f2 + fb + (size_t)(s * 512 + tid) * 4, z);
      }
    }
    // no trailing barrier: ofl/o12s next written >=2 barriers into step t+1
  }

  // final h states
  for (int i = tid; i < 4096; i += 512) {
    int r = i >> 6, c0 = (i & 63) << 2;
    int li = r * 256 + (c0 ^ ((r & 7) << 3));
    size_t g = (size_t)(r0 + r) * 256 + c0;
    s16x4 s1 = *(const s16x4*)&h1s[li];
    s16x4 s2 = *(const s16x4*)&h2s[li];
    s16x4 s3 = *(const s16x4*)&h3s[li];
    nt_st4(out_h1 + g, (f32x4){bf2f(s1[0]), bf2f(s1[1]), bf2f(s1[2]), bf2f(s1[3])});
    nt_st4(out_h2 + g, (f32x4){bf2f(s2[0]), bf2f(s2[1]), bf2f(s2[2]), bf2f(s2[3])});
    nt_st4(out_h3 + g, (f32x4){bf2f(s3[0]), bf2f(s3[1]), bf2f(s3[2]), bf2f(s3[3])});
  }
}

extern "C" void kernel_launch(void* const* d_in, const int* in_sizes, int n_in,
                              void* d_out, int out_size, void* d_ws, size_t ws_size,
                              hipStream_t stream) {
  const float* x   = (const float*)d_in[0];
  const float* cue = (const float*)d_in[1];
  const float* hc1 = (const float*)d_in[2];
  const float* hc2 = (const float*)d_in[3];
  const float* hc3 = (const float*)d_in[4];
  const float* hc4 = (const float*)d_in[5];
  PrepPtrs pp;
  pp.w1i = (const float*)d_in[6];  pp.b1i = (const float*)d_in[7];
  pp.w1h = (const float*)d_in[8];  pp.b1h = (const float*)d_in[9];
  pp.w1o = (const float*)d_in[10]; pp.bo1 = (const float*)d_in[11];
  pp.w2i = (const float*)d_in[12]; pp.b2i = (const float*)d_in[13];
  pp.w2h = (const float*)d_in[14]; pp.b2h = (const float*)d_in[15];
  pp.w2o = (const float*)d_in[16]; pp.bo2 = (const float*)d_in[17];
  pp.w3i = (const float*)d_in[18]; pp.b3i = (const float*)d_in[19];
  pp.w3h = (const float*)d_in[20]; pp.b3h = (const float*)d_in[21];
  pp.w3o = (const float*)d_in[22]; pp.bo3 = (const float*)d_in[23];
  pp.wfc = (const float*)d_in[24]; pp.bfc = (const float*)d_in[25];

  short* wpk   = (short*)d_ws;                       // 311296 bf16 = 622592 B
  float* wmisc = (float*)((char*)d_ws + 622592);     // 1602 f32

  prep_kernel<<<64, 256, 0, stream>>>(pp, wpk, wmisc);
  rnn_main<<<256, 512, 0, stream>>>(x, cue, hc1, hc2, hc3, hc4, wpk, wmisc, (float*)d_out);
}

// Round 12
// 741.582 us; speedup vs baseline: 1.6329x; 1.1316x over previous
//
#include <hip/hip_runtime.h>
#include <stdint.h>
#include <stddef.h>

// RNN_arch_2_final: 3-cell stacked RNN, T=16, B=16384, hidden 256.
// R12: R8 geometry (512thr/64-row/256WG), SUBTRACTIVE round: no persistent
// or prefetch register arrays (they spilled in R3/R5/R7/R8/R11); in-loop
// barriers are non-draining `s_waitcnt lgkmcnt(0); s_barrier` so NT stores
// ack in background and weight loads survive barriers. Folded streaming.

#define BN 16384
#define TT 16

typedef short s16x8 __attribute__((ext_vector_type(8)));
typedef short s16x4 __attribute__((ext_vector_type(4)));
typedef float f32x4 __attribute__((ext_vector_type(4)));

#define MFMA(a, b, c) __builtin_amdgcn_mfma_f32_16x16x32_bf16((a), (b), (c), 0, 0, 0)
// LDS-ordering barrier WITHOUT vmcnt drain. Safe: only LDS carries
// cross-wave hazards in the t-loop; global reads are read-only, global
// stores have no in-kernel readers.
#define BAR() asm volatile("s_waitcnt lgkmcnt(0)\n\ts_barrier" ::: "memory")

__device__ __forceinline__ short f2bf(float f) {
  union { float f; uint32_t u; } v; v.f = f;
  uint32_t u = v.u;
  u += 0x7FFFu + ((u >> 16) & 1u);   // RNE
  return (short)(u >> 16);
}
__device__ __forceinline__ float bf2f(short s) {
  union { uint32_t u; float f; } v; v.u = ((uint32_t)(uint16_t)s) << 16;
  return v.f;
}
__device__ __forceinline__ float fast_tanh(float xx) {
  float x = fminf(8.f, fmaxf(-8.f, xx));
  float e = __expf(2.f * x);
  return (e - 1.f) * __builtin_amdgcn_rcpf(e + 1.f);
}
__device__ __forceinline__ void nt_st4(float* p, f32x4 v) {
  __builtin_nontemporal_store(v, (f32x4*)p);
}
__device__ __forceinline__ f32x4 nt_ld4(const float* p) {
  return __builtin_nontemporal_load((const f32x4*)p);
}

struct PrepPtrs {
  const float *w1i, *w1h, *w1o, *w2i, *w2h, *w2o, *w3i, *w3h, *w3o;
  const float *b1i, *b1h, *b2i, *b2h, *b3i, *b3h, *bo1, *bo2, *bo3, *wfc, *bfc;
};

// Pack W[n][k] fragments: frag(kt,nt): elem(lane,e) = W[nt*16+(lane&15)][kt*32+(lane>>4)*8+e]
__global__ void prep_kernel(PrepPtrs pp, short* __restrict__ wpk, float* __restrict__ wmisc) {
  const float* P[9] = {pp.w1i, pp.w1h, pp.w1o, pp.w2i, pp.w2h, pp.w2o, pp.w3i, pp.w3h, pp.w3o};
  const int LD_[9] = {64, 256, 256, 64, 256, 256, 130, 256, 256};
  const int C0_[9] = {0, 0, 0, 0, 0, 0, 2, 0, 0};
  const int NT_[9] = {16, 16, 4, 16, 16, 4, 16, 16, 4};
  const int DO_[10] = {0, 16384, 81920, 98304, 114688, 180224, 196608, 229376, 294912, 311296};
  int stride = gridDim.x * blockDim.x;
  for (int g = blockIdx.x * blockDim.x + threadIdx.x; g < 311296; g += stride) {
    int m = 0;
    while (g >= DO_[m + 1]) ++m;
    int p = g - DO_[m];
    int NT = NT_[m];
    int frag = p >> 9, lane = (p >> 3) & 63, e = p & 7;
    int kt = frag / NT, nt = frag - kt * NT;
    int row = nt * 16 + (lane & 15);
    int col = kt * 32 + ((lane >> 4) << 3) + e;
    wpk[g] = f2bf(P[m][(size_t)row * LD_[m] + C0_[m] + col]);
  }
  for (int i = blockIdx.x * blockDim.x + threadIdx.x; i < 1602; i += stride) {
    float v;
    if      (i < 256)  v = pp.b1i[i]         + pp.b1h[i];
    else if (i < 512)  v = pp.b2i[i - 256]   + pp.b2h[i - 256];
    else if (i < 768)  v = pp.b3i[i - 512]   + pp.b3h[i - 512];
    else if (i < 832)  v = pp.bo1[i - 768];
    else if (i < 896)  v = pp.bo2[i - 832];
    else if (i < 960)  v = pp.bo3[i - 896];
    else if (i < 1088) v = pp.wfc[i - 960];
    else if (i < 1090) v = pp.bfc[i - 1088];
    else if (i < 1346) v = pp.w3i[(size_t)(i - 1090) * 130];
    else               v = pp.w3i[(size_t)(i - 1346) * 130 + 1];
    wmisc[i] = v;
  }
}

__launch_bounds__(512, 2)
__global__ void rnn_main(const float* __restrict__ x, const float* __restrict__ cue,
                         const float* __restrict__ hc1, const float* __restrict__ hc2,
                         const float* __restrict__ hc3, const float* __restrict__ hc4,
                         const short* __restrict__ wpk, const float* __restrict__ wmisc,
                         float* __restrict__ out) {
  // h LDS: element (r,c) at [r*256 + (c ^ ((r&7)<<3))]  (16-B granule XOR swizzle)
  __shared__ __align__(16) short h1s[64 * 256];
  __shared__ __align__(16) short h2s[64 * 256];
  __shared__ __align__(16) short h3s[64 * 256];
  __shared__ __align__(16) short o12s[64 * 128];   // o1 cols 0..63, o2 cols 64..127
  __shared__ __align__(16) float ofl[64 * 72];     // padded f32
  __shared__ float cue0[64], cue1[64];
  __shared__ __align__(16) float misc[1604];

  const int tid = threadIdx.x;
  const int wv = tid >> 6;          // 0..7
  const int lane = tid & 63;
  const int lr = lane & 15;
  const int lq = lane >> 4;
  const int swz = (lr & 7) << 3;
  const int r0 = blockIdx.x * 64;

  float* out_ys  = out;
  float* out_h1  = out + 524288;
  float* out_h2  = out + 4718592;
  float* out_h3  = out + 8912896;
  float* out_h4  = out + 13107200;
  float* out_o1s = out + 17301504;
  float* out_o2s = out + 34078720;
  float* out_cue = out + 50855936;
  float* out_f1  = out + 51380224;
  float* out_f2  = out + 118489088;
  float* out_of  = out + 185597952;

  for (int i = tid; i < 1602; i += 512) misc[i] = wmisc[i];
  if (tid < 64) {
    float cv = cue[r0 + tid];
    cue0[tid] = cv * 10.f;
    cue1[tid] = 10.f * fabsf(cv - 1.f);
  }
  // stage initial h (f32 -> bf16, swizzled) + h4 passthrough
  for (int i = tid; i < 4096; i += 512) {
    int r = i >> 6, c0 = (i & 63) << 2;
    int li = r * 256 + (c0 ^ ((r & 7) << 3));
    size_t g = (size_t)(r0 + r) * 256 + c0;
    f32x4 v1 = __builtin_nontemporal_load((const f32x4*)(hc1 + g));
    f32x4 v2 = __builtin_nontemporal_load((const f32x4*)(hc2 + g));
    f32x4 v3 = __builtin_nontemporal_load((const f32x4*)(hc3 + g));
    f32x4 v4 = __builtin_nontemporal_load((const f32x4*)(hc4 + g));
    *(s16x4*)&h1s[li] = (s16x4){f2bf(v1.x), f2bf(v1.y), f2bf(v1.z), f2bf(v1.w)};
    *(s16x4*)&h2s[li] = (s16x4){f2bf(v2.x), f2bf(v2.y), f2bf(v2.z), f2bf(v2.w)};
    *(s16x4*)&h3s[li] = (s16x4){f2bf(v3.x), f2bf(v3.y), f2bf(v3.z), f2bf(v3.w)};
    nt_st4(out_h4 + g, v4);
  }
  __syncthreads();

  const short* Wp1i  = wpk;
  const short* Wp1h  = wpk + 16384;
  const short* Wp1o  = wpk + 81920;
  const short* Wp2i  = wpk + 98304;
  const short* Wp2h  = wpk + 114688;
  const short* Wp2o  = wpk + 180224;
  const short* Wp3ab = wpk + 196608;
  const short* Wp3h  = wpk + 229376;
  const short* Wp3o  = wpk + 294912;
  const float* bh1v = misc;
  const float* bh2v = misc + 256;
  const float* bh3v = misc + 512;
  const float* bo1v = misc + 768;
  const float* bo2v = misc + 832;
  const float* bofv = misc + 896;
  const float* wfcv = misc + 960;
  const float* bfcv = misc + 1088;
  const float* w3c0 = misc + 1090;
  const float* w3c1 = misc + 1346;

  for (int t = 0; t < TT; ++t) {
    // ---------- Phase A: h1new/h2new; acc[rt][j], lane holds 4 consecutive n
    f32x4 acc1[4][2], acc2[4][2];
    #pragma unroll
    for (int j = 0; j < 2; ++j) {
      int nb = (2 * wv + j) * 16 + lq * 4;
      f32x4 b1 = *(const f32x4*)(bh1v + nb);
      f32x4 b2 = *(const f32x4*)(bh2v + nb);
      #pragma unroll
      for (int rt = 0; rt < 4; ++rt) { acc1[rt][j] = b1; acc2[rt][j] = b2; }
    }
    // x part
    #pragma unroll
    for (int kt = 0; kt < 2; ++kt) {
      s16x8 xbk[4];
      #pragma unroll
      for (int rt = 0; rt < 4; ++rt) {
        const float* px = x + ((size_t)t * BN + r0 + rt * 16 + lr) * 64 + kt * 32 + lq * 8;
        f32x4 a0 = nt_ld4(px);
        f32x4 a1 = nt_ld4(px + 4);
        xbk[rt] = (s16x8){f2bf(a0.x), f2bf(a0.y), f2bf(a0.z), f2bf(a0.w),
                          f2bf(a1.x), f2bf(a1.y), f2bf(a1.z), f2bf(a1.w)};
      }
      s16x8 a1w0 = *(const s16x8*)(Wp1i + ((size_t)(kt * 16 + 2 * wv) * 64 + lane) * 8);
      s16x8 a1w1 = *(const s16x8*)(Wp1i + ((size_t)(kt * 16 + 2 * wv + 1) * 64 + lane) * 8);
      s16x8 a2w0 = *(const s16x8*)(Wp2i + ((size_t)(kt * 16 + 2 * wv) * 64 + lane) * 8);
      s16x8 a2w1 = *(const s16x8*)(Wp2i + ((size_t)(kt * 16 + 2 * wv + 1) * 64 + lane) * 8);
      #pragma unroll
      for (int rt = 0; rt < 4; ++rt) {
        acc1[rt][0] = MFMA(a1w0, xbk[rt], acc1[rt][0]);
        acc1[rt][1] = MFMA(a1w1, xbk[rt], acc1[rt][1]);
        acc2[rt][0] = MFMA(a2w0, xbk[rt], acc2[rt][0]);
        acc2[rt][1] = MFMA(a2w1, xbk[rt], acc2[rt][1]);
      }
    }
    // recurrent
    #pragma unroll
    for (int kt = 0; kt < 8; ++kt) {
      s16x8 w1_0 = *(const s16x8*)(Wp1h + ((size_t)(kt * 16 + 2 * wv) * 64 + lane) * 8);
      s16x8 w1_1 = *(const s16x8*)(Wp1h + ((size_t)(kt * 16 + 2 * wv + 1) * 64 + lane) * 8);
      s16x8 w2_0 = *(const s16x8*)(Wp2h + ((size_t)(kt * 16 + 2 * wv) * 64 + lane) * 8);
      s16x8 w2_1 = *(const s16x8*)(Wp2h + ((size_t)(kt * 16 + 2 * wv + 1) * 64 + lane) * 8);
      s16x8 hb1[4], hb2[4];
      #pragma unroll
      for (int rt = 0; rt < 4; ++rt) {
        int ad = (rt * 16 + lr) * 256 + ((kt * 32 + lq * 8) ^ swz);
        hb1[rt] = *(const s16x8*)&h1s[ad];
        hb2[rt] = *(const s16x8*)&h2s[ad];
      }
      #pragma unroll
      for (int rt = 0; rt < 4; ++rt) {
        acc1[rt][0] = MFMA(w1_0, hb1[rt], acc1[rt][0]);
        acc1[rt][1] = MFMA(w1_1, hb1[rt], acc1[rt][1]);
        acc2[rt][0] = MFMA(w2_0, hb2[rt], acc2[rt][0]);
        acc2[rt][1] = MFMA(w2_1, hb2[rt], acc2[rt][1]);
      }
    }
    BAR();   // all done reading old h1/h2 (no vmcnt drain)
    #pragma unroll
    for (int j = 0; j < 2; ++j) {
      int cb = (2 * wv + j) * 16 + lq * 4;
      #pragma unroll
      for (int rt = 0; rt < 4; ++rt) {
        int ad = (rt * 16 + lr) * 256 + (cb ^ swz);
        *(s16x4*)&h1s[ad] = (s16x4){f2bf(fast_tanh(acc1[rt][j][0])), f2bf(fast_tanh(acc1[rt][j][1])),
                                    f2bf(fast_tanh(acc1[rt][j][2])), f2bf(fast_tanh(acc1[rt][j][3]))};
        *(s16x4*)&h2s[ad] = (s16x4){f2bf(fast_tanh(acc2[rt][j][0])), f2bf(fast_tanh(acc2[rt][j][1])),
                                    f2bf(fast_tanh(acc2[rt][j][2])), f2bf(fast_tanh(acc2[rt][j][3]))};
      }
    }
    BAR();

    // ---------- Phase B: o1 (waves 0-3) / o2 (waves 4-7)
    {
      int cell = wv >> 2, w4 = wv & 3;
      const short* hs = cell ? h2s : h1s;
      const short* Wo = cell ? Wp2o : Wp1o;
      const float* bo = cell ? bo2v : bo1v;
      int nb = w4 * 16 + lq * 4;
      f32x4 bb = *(const f32x4*)(bo + nb);
      f32x4 acc[4];
      #pragma unroll
      for (int rt = 0; rt < 4; ++rt) acc[rt] = bb;
      #pragma unroll
      for (int kt = 0; kt < 8; ++kt) {
        s16x8 aw = *(const s16x8*)(Wo + ((size_t)(kt * 4 + w4) * 64 + lane) * 8);
        #pragma unroll
        for (int rt = 0; rt < 4; ++rt) {
          s16x8 hb = *(const s16x8*)&hs[(rt * 16 + lr) * 256 + ((kt * 32 + lq * 8) ^ swz)];
          acc[rt] = MFMA(aw, hb, acc[rt]);
        }
      }
      int cb = cell * 64 + nb;
      #pragma unroll
      for (int rt = 0; rt < 4; ++rt) {
        *(s16x4*)&o12s[(rt * 16 + lr) * 128 + (cb ^ swz)] =
            (s16x4){f2bf(fast_tanh(acc[rt][0])), f2bf(fast_tanh(acc[rt][1])),
                    f2bf(fast_tanh(acc[rt][2])), f2bf(fast_tanh(acc[rt][3]))};
      }
    }
    BAR();

    // ---------- Phase C: h3new (all weights streamed inline)
    {
      f32x4 acc3[4][2];
      #pragma unroll
      for (int j = 0; j < 2; ++j) {
        int nb = (2 * wv + j) * 16 + lq * 4;
        f32x4 bb  = *(const f32x4*)(bh3v + nb);
        f32x4 c0w = *(const f32x4*)(w3c0 + nb);
        f32x4 c1w = *(const f32x4*)(w3c1 + nb);
        #pragma unroll
        for (int rt = 0; rt < 4; ++rt) {
          float cz = cue0[rt * 16 + lr], co = cue1[rt * 16 + lr];
          acc3[rt][j] = bb + cz * c0w + co * c1w;
        }
      }
      #pragma unroll
      for (int kt = 0; kt < 4; ++kt) {   // [o1|o2], K=128
        s16x8 aw0 = *(const s16x8*)(Wp3ab + ((size_t)(kt * 16 + 2 * wv) * 64 + lane) * 8);
        s16x8 aw1 = *(const s16x8*)(Wp3ab + ((size_t)(kt * 16 + 2 * wv + 1) * 64 + lane) * 8);
        #pragma unroll
        for (int rt = 0; rt < 4; ++rt) {
          s16x8 ob = *(const s16x8*)&o12s[(rt * 16 + lr) * 128 + ((kt * 32 + lq * 8) ^ swz)];
          acc3[rt][0] = MFMA(aw0, ob, acc3[rt][0]);
          acc3[rt][1] = MFMA(aw1, ob, acc3[rt][1]);
        }
      }
      #pragma unroll
      for (int kt = 0; kt < 8; ++kt) {   // recurrent, K=256
        s16x8 aw0 = *(const s16x8*)(Wp3h + ((size_t)(kt * 16 + 2 * wv) * 64 + lane) * 8);
        s16x8 aw1 = *(const s16x8*)(Wp3h + ((size_t)(kt * 16 + 2 * wv + 1) * 64 + lane) * 8);
        #pragma unroll
        for (int rt = 0; rt < 4; ++rt) {
          s16x8 hb = *(const s16x8*)&h3s[(rt * 16 + lr) * 256 + ((kt * 32 + lq * 8) ^ swz)];
          acc3[rt][0] = MFMA(aw0, hb, acc3[rt][0]);
          acc3[rt][1] = MFMA(aw1, hb, acc3[rt][1]);
        }
      }
      BAR();   // done reading old h3
      #pragma unroll
      for (int j = 0; j < 2; ++j) {
        int cb = (2 * wv + j) * 16 + lq * 4;
        #pragma unroll
        for (int rt = 0; rt < 4; ++rt) {
          *(s16x4*)&h3s[(rt * 16 + lr) * 256 + (cb ^ swz)] =
              (s16x4){f2bf(fast_tanh(acc3[rt][j][0])), f2bf(fast_tanh(acc3[rt][j][1])),
                      f2bf(fast_tanh(acc3[rt][j][2])), f2bf(fast_tanh(acc3[rt][j][3]))};
        }
      }
      BAR();
    }

    // ---------- Phase D: waves 0-3 compute of; waves 4-7 store o1s/o2s (NT)
    if (wv < 4) {
      int nb = wv * 16 + lq * 4;
      f32x4 bb = *(const f32x4*)(bofv + nb);
      f32x4 acc[4];
      #pragma unroll
      for (int rt = 0; rt < 4; ++rt) acc[rt] = bb;
      #pragma unroll
      for (int kt = 0; kt < 8; ++kt) {
        s16x8 aw = *(const s16x8*)(Wp3o + ((size_t)(kt * 4 + wv) * 64 + lane) * 8);
        #pragma unroll
        for (int rt = 0; rt < 4; ++rt) {
          s16x8 hb = *(const s16x8*)&h3s[(rt * 16 + lr) * 256 + ((kt * 32 + lq * 8) ^ swz)];
          acc[rt] = MFMA(aw, hb, acc[rt]);
        }
      }
      #pragma unroll
      for (int rt = 0; rt < 4; ++rt) {
        f32x4 v = (f32x4){fmaxf(0.f, acc[rt][0]), fmaxf(0.f, acc[rt][1]),
                          fmaxf(0.f, acc[rt][2]), fmaxf(0.f, acc[rt][3])};
        *(f32x4*)&ofl[(rt * 16 + lr) * 72 + nb] = v;
      }
    } else {
      size_t ob = ((size_t)t * BN + r0) * 64;
      float* targ = (wv < 6) ? out_o1s : out_o2s;
      int coff = (wv < 6) ? 0 : 64;
      int wq = wv & 1;
      #pragma unroll
      for (int s = 0; s < 8; ++s) {
        int f = wq * 2048 + s * 256 + lane * 4;
        int r = f >> 6, c = f & 63;
        s16x4 v = *(const s16x4*)&o12s[r * 128 + ((c + coff) ^ ((r & 7) << 3))];
        nt_st4(targ + ob + f, (f32x4){bf2f(v[0]), bf2f(v[1]), bf2f(v[2]), bf2f(v[3])});
      }
    }
    BAR();

    // ---------- Phase E: of store + y + cue_arr + feed zero-fill (NT)
    {
      size_t ob = ((size_t)t * BN + r0) * 64;
      int r = tid >> 3, c0 = (tid & 7) << 3;
      nt_st4(out_of + ob + r * 64 + c0,     *(const f32x4*)&ofl[r * 72 + c0]);
      nt_st4(out_of + ob + r * 64 + c0 + 4, *(const f32x4*)&ofl[r * 72 + c0 + 4]);
      if (tid < 128) {
        int rr = tid >> 1, jj = tid & 1;
        const f32x4* wr4 = (const f32x4*)(wfcv + jj * 64);
        const f32x4* or4 = (const f32x4*)&ofl[rr * 72];
        f32x4 sv = (f32x4){0.f, 0.f, 0.f, 0.f};
        #pragma unroll
        for (int kk = 0; kk < 16; ++kk) sv += or4[kk] * wr4[kk];
        float s = bfcv[jj] + sv[0] + sv[1] + sv[2] + sv[3];
        size_t yi = ((size_t)t * BN + r0 + rr) * 2 + jj;
        __builtin_nontemporal_store(s, out_ys + yi);
        __builtin_nontemporal_store(jj ? cue1[rr] : cue0[rr], out_cue + yi);
      }
      size_t fb = ((size_t)t * BN + r0) * 256;   // 16384 floats per feed array
      f32x4 z = (f32x4){0.f, 0.f, 0.f, 0.f};
      #pragma unroll
      for (int s = 0; s < 8; ++s) {
        nt_st4(out_f1 + fb + (size_t)(s * 512 + tid) * 4, z);
        nt_st4(out_f2 + fb + (size_t)(s * 512 + tid) * 4, z);
      }
    }
    // no trailing barrier: ofl/o12s next written >=2 barriers into step t+1
  }

  // final h states
  for (int i = tid; i < 4096; i += 512) {
    int r = i >> 6, c0 = (i & 63) << 2;
    int li = r * 256 + (c0 ^ ((r & 7) << 3));
    size_t g = (size_t)(r0 + r) * 256 + c0;
    s16x4 s1 = *(const s16x4*)&h1s[li];
    s16x4 s2 = *(const s16x4*)&h2s[li];
    s16x4 s3 = *(const s16x4*)&h3s[li];
    nt_st4(out_h1 + g, (f32x4){bf2f(s1[0]), bf2f(s1[1]), bf2f(s1[2]), bf2f(s1[3])});
    nt_st4(out_h2 + g, (f32x4){bf2f(s2[0]), bf2f(s2[1]), bf2f(s2[2]), bf2f(s2[3])});
    nt_st4(out_h3 + g, (f32x4){bf2f(s3[0]), bf2f(s3[1]), bf2f(s3[2]), bf2f(s3[3])});
  }
}

extern "C" void kernel_launch(void* const* d_in, const int* in_sizes, int n_in,
                              void* d_out, int out_size, void* d_ws, size_t ws_size,
                              hipStream_t stream) {
  const float* x   = (const float*)d_in[0];
  const float* cue = (const float*)d_in[1];
  const float* hc1 = (const float*)d_in[2];
  const float* hc2 = (const float*)d_in[3];
  const float* hc3 = (const float*)d_in[4];
  const float* hc4 = (const float*)d_in[5];
  PrepPtrs pp;
  pp.w1i = (const float*)d_in[6];  pp.b1i = (const float*)d_in[7];
  pp.w1h = (const float*)d_in[8];  pp.b1h = (const float*)d_in[9];
  pp.w1o = (const float*)d_in[10]; pp.bo1 = (const float*)d_in[11];
  pp.w2i = (const float*)d_in[12]; pp.b2i = (const float*)d_in[13];
  pp.w2h = (const float*)d_in[14]; pp.b2h = (const float*)d_in[15];
  pp.w2o = (const float*)d_in[16]; pp.bo2 = (const float*)d_in[17];
  pp.w3i = (const float*)d_in[18]; pp.b3i = (const float*)d_in[19];
  pp.w3h = (const float*)d_in[20]; pp.b3h = (const float*)d_in[21];
  pp.w3o = (const float*)d_in[22]; pp.bo3 = (const float*)d_in[23];
  pp.wfc = (const float*)d_in[24]; pp.bfc = (const float*)d_in[25];

  short* wpk   = (short*)d_ws;                       // 311296 bf16 = 622592 B
  float* wmisc = (float*)((char*)d_ws + 622592);     // 1602 f32

  prep_kernel<<<64, 256, 0, stream>>>(pp, wpk, wmisc);
  rnn_main<<<256, 512, 0, stream>>>(x, cue, hc1, hc2, hc3, hc4, wpk, wmisc, (float*)d_out);
}

// Round 13
// 564.583 us; speedup vs baseline: 2.1448x; 1.3135x over previous
//
#include <hip/hip_runtime.h>
#include <stdint.h>
#include <stddef.h>

// RNN_arch_2_final: 3-cell stacked RNN, T=16, B=16384, hidden 256.
// R13: R8 geometry (512thr/64-row/256WG). Phase A split A1(cell1)->A2(cell2)
// with h1new parked in an LDS scratch region (unioned with o12s/ofl) so only
// 32 acc VGPRs are live at once -> kills the standing ~135MB/run scratch
// spill seen in R4/R8/R12. x staged once/step into an 8KB LDS tile (was
// redundantly loaded by all 8 waves). __syncthreads barriers (BAR regressed).

#define BN 16384
#define TT 16

typedef short s16x8 __attribute__((ext_vector_type(8)));
typedef short s16x4 __attribute__((ext_vector_type(4)));
typedef float f32x4 __attribute__((ext_vector_type(4)));

#define MFMA(a, b, c) __builtin_amdgcn_mfma_f32_16x16x32_bf16((a), (b), (c), 0, 0, 0)

__device__ __forceinline__ short f2bf(float f) {
  union { float f; uint32_t u; } v; v.f = f;
  uint32_t u = v.u;
  u += 0x7FFFu + ((u >> 16) & 1u);   // RNE
  return (short)(u >> 16);
}
__device__ __forceinline__ float bf2f(short s) {
  union { uint32_t u; float f; } v; v.u = ((uint32_t)(uint16_t)s) << 16;
  return v.f;
}
__device__ __forceinline__ float fast_tanh(float xx) {
  float x = fminf(8.f, fmaxf(-8.f, xx));
  float e = __expf(2.f * x);
  return (e - 1.f) * __builtin_amdgcn_rcpf(e + 1.f);
}
__device__ __forceinline__ void nt_st4(float* p, f32x4 v) {
  __builtin_nontemporal_store(v, (f32x4*)p);
}
__device__ __forceinline__ f32x4 nt_ld4(const float* p) {
  return __builtin_nontemporal_load((const f32x4*)p);
}

struct PrepPtrs {
  const float *w1i, *w1h, *w1o, *w2i, *w2h, *w2o, *w3i, *w3h, *w3o;
  const float *b1i, *b1h, *b2i, *b2h, *b3i, *b3h, *bo1, *bo2, *bo3, *wfc, *bfc;
};

// Pack W[n][k] fragments: frag(kt,nt): elem(lane,e) = W[nt*16+(lane&15)][kt*32+(lane>>4)*8+e]
__global__ void prep_kernel(PrepPtrs pp, short* __restrict__ wpk, float* __restrict__ wmisc) {
  const float* P[9] = {pp.w1i, pp.w1h, pp.w1o, pp.w2i, pp.w2h, pp.w2o, pp.w3i, pp.w3h, pp.w3o};
  const int LD_[9] = {64, 256, 256, 64, 256, 256, 130, 256, 256};
  const int C0_[9] = {0, 0, 0, 0, 0, 0, 2, 0, 0};
  const int NT_[9] = {16, 16, 4, 16, 16, 4, 16, 16, 4};
  const int DO_[10] = {0, 16384, 81920, 98304, 114688, 180224, 196608, 229376, 294912, 311296};
  int stride = gridDim.x * blockDim.x;
  for (int g = blockIdx.x * blockDim.x + threadIdx.x; g < 311296; g += stride) {
    int m = 0;
    while (g >= DO_[m + 1]) ++m;
    int p = g - DO_[m];
    int NT = NT_[m];
    int frag = p >> 9, lane = (p >> 3) & 63, e = p & 7;
    int kt = frag / NT, nt = frag - kt * NT;
    int row = nt * 16 + (lane & 15);
    int col = kt * 32 + ((lane >> 4) << 3) + e;
    wpk[g] = f2bf(P[m][(size_t)row * LD_[m] + C0_[m] + col]);
  }
  for (int i = blockIdx.x * blockDim.x + threadIdx.x; i < 1602; i += stride) {
    float v;
    if      (i < 256)  v = pp.b1i[i]         + pp.b1h[i];
    else if (i < 512)  v = pp.b2i[i - 256]   + pp.b2h[i - 256];
    else if (i < 768)  v = pp.b3i[i - 512]   + pp.b3h[i - 512];
    else if (i < 832)  v = pp.bo1[i - 768];
    else if (i < 896)  v = pp.bo2[i - 832];
    else if (i < 960)  v = pp.bo3[i - 896];
    else if (i < 1088) v = pp.wfc[i - 960];
    else if (i < 1090) v = pp.bfc[i - 1088];
    else if (i < 1346) v = pp.w3i[(size_t)(i - 1090) * 130];
    else               v = pp.w3i[(size_t)(i - 1346) * 130 + 1];
    wmisc[i] = v;
  }
}

__launch_bounds__(512, 2)
__global__ void rnn_main(const float* __restrict__ x, const float* __restrict__ cue,
                         const float* __restrict__ hc1, const float* __restrict__ hc2,
                         const float* __restrict__ hc3, const float* __restrict__ hc4,
                         const short* __restrict__ wpk, const float* __restrict__ wmisc,
                         float* __restrict__ out) {
  // LDS pool. h tiles: element (r,c) at [r*256 + (c ^ ((r&7)<<3))].
  // Union region (o12s+ofl | hscr): hscr only live A1-epi..A2-epi copy;
  // o12s written in B (fully), ofl written in D (fully) - no temporal overlap.
  __shared__ __align__(16) char pool[141312];
  short* h1s  = (short*)pool;                    // 32768 B
  short* h2s  = (short*)(pool + 32768);          // 32768 B
  short* h3s  = (short*)(pool + 65536);          // 32768 B
  short* o12s = (short*)(pool + 98304);          // 16384 B  (union w/ hscr)
  float* ofl  = (float*)(pool + 114688);         // 18432 B  (union w/ hscr tail)
  short* hscr = (short*)(pool + 98304);          // 32768 B  scratch for h1new
  short* xls  = (short*)(pool + 133120);         // 8192 B   x tile (bf16, swz)
  __shared__ float cue0[64], cue1[64];
  __shared__ __align__(16) float misc[1604];

  const int tid = threadIdx.x;
  const int wv = tid >> 6;          // 0..7
  const int lane = tid & 63;
  const int lr = lane & 15;
  const int lq = lane >> 4;
  const int swz = (lr & 7) << 3;
  const int r0 = blockIdx.x * 64;

  float* out_ys  = out;
  float* out_h1  = out + 524288;
  float* out_h2  = out + 4718592;
  float* out_h3  = out + 8912896;
  float* out_h4  = out + 13107200;
  float* out_o1s = out + 17301504;
  float* out_o2s = out + 34078720;
  float* out_cue = out + 50855936;
  float* out_f1  = out + 51380224;
  float* out_f2  = out + 118489088;
  float* out_of  = out + 185597952;

  for (int i = tid; i < 1602; i += 512) misc[i] = wmisc[i];
  if (tid < 64) {
    float cv = cue[r0 + tid];
    cue0[tid] = cv * 10.f;
    cue1[tid] = 10.f * fabsf(cv - 1.f);
  }
  // stage initial h (f32 -> bf16, swizzled) + h4 passthrough
  for (int i = tid; i < 4096; i += 512) {
    int r = i >> 6, c0 = (i & 63) << 2;
    int li = r * 256 + (c0 ^ ((r & 7) << 3));
    size_t g = (size_t)(r0 + r) * 256 + c0;
    f32x4 v1 = __builtin_nontemporal_load((const f32x4*)(hc1 + g));
    f32x4 v2 = __builtin_nontemporal_load((const f32x4*)(hc2 + g));
    f32x4 v3 = __builtin_nontemporal_load((const f32x4*)(hc3 + g));
    f32x4 v4 = __builtin_nontemporal_load((const f32x4*)(hc4 + g));
    *(s16x4*)&h1s[li] = (s16x4){f2bf(v1.x), f2bf(v1.y), f2bf(v1.z), f2bf(v1.w)};
    *(s16x4*)&h2s[li] = (s16x4){f2bf(v2.x), f2bf(v2.y), f2bf(v2.z), f2bf(v2.w)};
    *(s16x4*)&h3s[li] = (s16x4){f2bf(v3.x), f2bf(v3.y), f2bf(v3.z), f2bf(v3.w)};
    nt_st4(out_h4 + g, v4);
  }
  __syncthreads();

  const short* Wp1i  = wpk;
  const short* Wp1h  = wpk + 16384;
  const short* Wp1o  = wpk + 81920;
  const short* Wp2i  = wpk + 98304;
  const short* Wp2h  = wpk + 114688;
  const short* Wp2o  = wpk + 180224;
  const short* Wp3ab = wpk + 196608;
  const short* Wp3h  = wpk + 229376;
  const short* Wp3o  = wpk + 294912;
  const float* bh1v = misc;
  const float* bh2v = misc + 256;
  const float* bh3v = misc + 512;
  const float* bo1v = misc + 768;
  const float* bo2v = misc + 832;
  const float* bofv = misc + 896;
  const float* wfcv = misc + 960;
  const float* bfcv = misc + 1088;
  const float* w3c0 = misc + 1090;
  const float* w3c1 = misc + 1346;

  for (int t = 0; t < TT; ++t) {
    // ---------- x stage: 64x64 f32 -> bf16 LDS tile (swizzled), once per step
    {
      int r = tid >> 3, cq = (tid & 7) << 3;
      const float* px = x + ((size_t)t * BN + r0 + r) * 64 + cq;
      f32x4 a0 = nt_ld4(px);
      f32x4 a1 = nt_ld4(px + 4);
      *(s16x8*)&xls[r * 64 + (cq ^ ((r & 7) << 3))] =
          (s16x8){f2bf(a0.x), f2bf(a0.y), f2bf(a0.z), f2bf(a0.w),
                  f2bf(a1.x), f2bf(a1.y), f2bf(a1.z), f2bf(a1.w)};
    }
    __syncthreads();   // bar0: xls ready; also fences E(t-1)'s ofl reads vs hscr

    // ---------- Phase A1: cell 1 only (acc1 = 32 VGPRs live)
    {
      f32x4 acc1[4][2];
      #pragma unroll
      for (int j = 0; j < 2; ++j) {
        int nb = (2 * wv + j) * 16 + lq * 4;
        f32x4 b1 = *(const f32x4*)(bh1v + nb);
        #pragma unroll
        for (int rt = 0; rt < 4; ++rt) acc1[rt][j] = b1;
      }
      #pragma unroll
      for (int kt = 0; kt < 2; ++kt) {   // x part, K=64 (from LDS)
        s16x8 aw0 = *(const s16x8*)(Wp1i + ((size_t)(kt * 16 + 2 * wv) * 64 + lane) * 8);
        s16x8 aw1 = *(const s16x8*)(Wp1i + ((size_t)(kt * 16 + 2 * wv + 1) * 64 + lane) * 8);
        #pragma unroll
        for (int rt = 0; rt < 4; ++rt) {
          s16x8 xb = *(const s16x8*)&xls[(rt * 16 + lr) * 64 + ((kt * 32 + lq * 8) ^ swz)];
          acc1[rt][0] = MFMA(aw0, xb, acc1[rt][0]);
          acc1[rt][1] = MFMA(aw1, xb, acc1[rt][1]);
        }
      }
      #pragma unroll
      for (int kt = 0; kt < 8; ++kt) {   // recurrent, K=256
        s16x8 aw0 = *(const s16x8*)(Wp1h + ((size_t)(kt * 16 + 2 * wv) * 64 + lane) * 8);
        s16x8 aw1 = *(const s16x8*)(Wp1h + ((size_t)(kt * 16 + 2 * wv + 1) * 64 + lane) * 8);
        #pragma unroll
        for (int rt = 0; rt < 4; ++rt) {
          s16x8 hb = *(const s16x8*)&h1s[(rt * 16 + lr) * 256 + ((kt * 32 + lq * 8) ^ swz)];
          acc1[rt][0] = MFMA(aw0, hb, acc1[rt][0]);
          acc1[rt][1] = MFMA(aw1, hb, acc1[rt][1]);
        }
      }
      // epi: park tanh(acc1) in hscr (NOT h1s) - no barrier needed, acc1 dies here
      #pragma unroll
      for (int j = 0; j < 2; ++j) {
        int cb = (2 * wv + j) * 16 + lq * 4;
        #pragma unroll
        for (int rt = 0; rt < 4; ++rt) {
          *(s16x4*)&hscr[(rt * 16 + lr) * 256 + (cb ^ swz)] =
              (s16x4){f2bf(fast_tanh(acc1[rt][j][0])), f2bf(fast_tanh(acc1[rt][j][1])),
                      f2bf(fast_tanh(acc1[rt][j][2])), f2bf(fast_tanh(acc1[rt][j][3]))};
        }
      }
    }

    // ---------- Phase A2: cell 2 (acc2 = 32 VGPRs live)
    {
      f32x4 acc2[4][2];
      #pragma unroll
      for (int j = 0; j < 2; ++j) {
        int nb = (2 * wv + j) * 16 + lq * 4;
        f32x4 b2 = *(const f32x4*)(bh2v + nb);
        #pragma unroll
        for (int rt = 0; rt < 4; ++rt) acc2[rt][j] = b2;
      }
      #pragma unroll
      for (int kt = 0; kt < 2; ++kt) {   // x part, K=64 (from LDS)
        s16x8 aw0 = *(const s16x8*)(Wp2i + ((size_t)(kt * 16 + 2 * wv) * 64 + lane) * 8);
        s16x8 aw1 = *(const s16x8*)(Wp2i + ((size_t)(kt * 16 + 2 * wv + 1) * 64 + lane) * 8);
        #pragma unroll
        for (int rt = 0; rt < 4; ++rt) {
          s16x8 xb = *(const s16x8*)&xls[(rt * 16 + lr) * 64 + ((kt * 32 + lq * 8) ^ swz)];
          acc2[rt][0] = MFMA(aw0, xb, acc2[rt][0]);
          acc2[rt][1] = MFMA(aw1, xb, acc2[rt][1]);
        }
      }
      #pragma unroll
      for (int kt = 0; kt < 8; ++kt) {   // recurrent, K=256
        s16x8 aw0 = *(const s16x8*)(Wp2h + ((size_t)(kt * 16 + 2 * wv) * 64 + lane) * 8);
        s16x8 aw1 = *(const s16x8*)(Wp2h + ((size_t)(kt * 16 + 2 * wv + 1) * 64 + lane) * 8);
        #pragma unroll
        for (int rt = 0; rt < 4; ++rt) {
          s16x8 hb = *(const s16x8*)&h2s[(rt * 16 + lr) * 256 + ((kt * 32 + lq * 8) ^ swz)];
          acc2[rt][0] = MFMA(aw0, hb, acc2[rt][0]);
          acc2[rt][1] = MFMA(aw1, hb, acc2[rt][1]);
        }
      }
      __syncthreads();   // bar2: h2s reads done, hscr fully written
      // epi: write h2new in place; copy hscr -> h1s (linear 16B chunks)
      #pragma unroll
      for (int j = 0; j < 2; ++j) {
        int cb = (2 * wv + j) * 16 + lq * 4;
        #pragma unroll
        for (int rt = 0; rt < 4; ++rt) {
          *(s16x4*)&h2s[(rt * 16 + lr) * 256 + (cb ^ swz)] =
              (s16x4){f2bf(fast_tanh(acc2[rt][j][0])), f2bf(fast_tanh(acc2[rt][j][1])),
                      f2bf(fast_tanh(acc2[rt][j][2])), f2bf(fast_tanh(acc2[rt][j][3]))};
        }
      }
      #pragma unroll
      for (int i = 0; i < 4; ++i) {
        int e = (i * 512 + tid) * 8;
        *(s16x8*)&h1s[e] = *(const s16x8*)&hscr[e];
      }
      __syncthreads();   // bar3: h1s/h2s ready
    }

    // ---------- Phase B: o1 (waves 0-3) / o2 (waves 4-7)
    {
      int cell = wv >> 2, w4 = wv & 3;
      const short* hs = cell ? h2s : h1s;
      const short* Wo = cell ? Wp2o : Wp1o;
      const float* bo = cell ? bo2v : bo1v;
      int nb = w4 * 16 + lq * 4;
      f32x4 bb = *(const f32x4*)(bo + nb);
      f32x4 acc[4];
      #pragma unroll
      for (int rt = 0; rt < 4; ++rt) acc[rt] = bb;
      #pragma unroll
      for (int kt = 0; kt < 8; ++kt) {
        s16x8 aw = *(const s16x8*)(Wo + ((size_t)(kt * 4 + w4) * 64 + lane) * 8);
        #pragma unroll
        for (int rt = 0; rt < 4; ++rt) {
          s16x8 hb = *(const s16x8*)&hs[(rt * 16 + lr) * 256 + ((kt * 32 + lq * 8) ^ swz)];
          acc[rt] = MFMA(aw, hb, acc[rt]);
        }
      }
      int cb = cell * 64 + nb;
      #pragma unroll
      for (int rt = 0; rt < 4; ++rt) {
        *(s16x4*)&o12s[(rt * 16 + lr) * 128 + (cb ^ swz)] =
            (s16x4){f2bf(fast_tanh(acc[rt][0])), f2bf(fast_tanh(acc[rt][1])),
                    f2bf(fast_tanh(acc[rt][2])), f2bf(fast_tanh(acc[rt][3]))};
      }
    }
    __syncthreads();

    // ---------- Phase C: h3new
    {
      f32x4 acc3[4][2];
      #pragma unroll
      for (int j = 0; j < 2; ++j) {
        int nb = (2 * wv + j) * 16 + lq * 4;
        f32x4 bb  = *(const f32x4*)(bh3v + nb);
        f32x4 c0w = *(const f32x4*)(w3c0 + nb);
        f32x4 c1w = *(const f32x4*)(w3c1 + nb);
        #pragma unroll
        for (int rt = 0; rt < 4; ++rt) {
          float cz = cue0[rt * 16 + lr], co = cue1[rt * 16 + lr];
          acc3[rt][j] = bb + cz * c0w + co * c1w;
        }
      }
      #pragma unroll
      for (int kt = 0; kt < 4; ++kt) {   // [o1|o2], K=128
        s16x8 aw0 = *(const s16x8*)(Wp3ab + ((size_t)(kt * 16 + 2 * wv) * 64 + lane) * 8);
        s16x8 aw1 = *(const s16x8*)(Wp3ab + ((size_t)(kt * 16 + 2 * wv + 1) * 64 + lane) * 8);
        #pragma unroll
        for (int rt = 0; rt < 4; ++rt) {
          s16x8 ob = *(const s16x8*)&o12s[(rt * 16 + lr) * 128 + ((kt * 32 + lq * 8) ^ swz)];
          acc3[rt][0] = MFMA(aw0, ob, acc3[rt][0]);
          acc3[rt][1] = MFMA(aw1, ob, acc3[rt][1]);
        }
      }
      #pragma unroll
      for (int kt = 0; kt < 8; ++kt) {   // recurrent, K=256
        s16x8 aw0 = *(const s16x8*)(Wp3h + ((size_t)(kt * 16 + 2 * wv) * 64 + lane) * 8);
        s16x8 aw1 = *(const s16x8*)(Wp3h + ((size_t)(kt * 16 + 2 * wv + 1) * 64 + lane) * 8);
        #pragma unroll
        for (int rt = 0; rt < 4; ++rt) {
          s16x8 hb = *(const s16x8*)&h3s[(rt * 16 + lr) * 256 + ((kt * 32 + lq * 8) ^ swz)];
          acc3[rt][0] = MFMA(aw0, hb, acc3[rt][0]);
          acc3[rt][1] = MFMA(aw1, hb, acc3[rt][1]);
        }
      }
      __syncthreads();   // done reading old h3
      #pragma unroll
      for (int j = 0; j < 2; ++j) {
        int cb = (2 * wv + j) * 16 + lq * 4;
        #pragma unroll
        for (int rt = 0; rt < 4; ++rt) {
          *(s16x4*)&h3s[(rt * 16 + lr) * 256 + (cb ^ swz)] =
              (s16x4){f2bf(fast_tanh(acc3[rt][j][0])), f2bf(fast_tanh(acc3[rt][j][1])),
                      f2bf(fast_tanh(acc3[rt][j][2])), f2bf(fast_tanh(acc3[rt][j][3]))};
        }
      }
      __syncthreads();
    }

    // ---------- Phase D: waves 0-3 compute of; waves 4-7 store o1s/o2s (NT)
    if (wv < 4) {
      int nb = wv * 16 + lq * 4;
      f32x4 bb = *(const f32x4*)(bofv + nb);
      f32x4 acc[4];
      #pragma unroll
      for (int rt = 0; rt < 4; ++rt) acc[rt] = bb;
      #pragma unroll
      for (int kt = 0; kt < 8; ++kt) {
        s16x8 aw = *(const s16x8*)(Wp3o + ((size_t)(kt * 4 + wv) * 64 + lane) * 8);
        #pragma unroll
        for (int rt = 0; rt < 4; ++rt) {
          s16x8 hb = *(const s16x8*)&h3s[(rt * 16 + lr) * 256 + ((kt * 32 + lq * 8) ^ swz)];
          acc[rt] = MFMA(aw, hb, acc[rt]);
        }
      }
      #pragma unroll
      for (int rt = 0; rt < 4; ++rt) {
        f32x4 v = (f32x4){fmaxf(0.f, acc[rt][0]), fmaxf(0.f, acc[rt][1]),
                          fmaxf(0.f, acc[rt][2]), fmaxf(0.f, acc[rt][3])};
        *(f32x4*)&ofl[(rt * 16 + lr) * 72 + nb] = v;
      }
    } else {
      size_t ob = ((size_t)t * BN + r0) * 64;
      float* targ = (wv < 6) ? out_o1s : out_o2s;
      int coff = (wv < 6) ? 0 : 64;
      int wq = wv & 1;
      #pragma unroll
      for (int s = 0; s < 8; ++s) {
        int f = wq * 2048 + s * 256 + lane * 4;
        int r = f >> 6, c = f & 63;
        s16x4 v = *(const s16x4*)&o12s[r * 128 + ((c + coff) ^ ((r & 7) << 3))];
        nt_st4(targ + ob + f, (f32x4){bf2f(v[0]), bf2f(v[1]), bf2f(v[2]), bf2f(v[3])});
      }
    }
    __syncthreads();

    // ---------- Phase E: of store + y + cue_arr + feed zero-fill (NT)
    {
      size_t ob = ((size_t)t * BN + r0) * 64;
      int r = tid >> 3, c0 = (tid & 7) << 3;
      nt_st4(out_of + ob + r * 64 + c0,     *(const f32x4*)&ofl[r * 72 + c0]);
      nt_st4(out_of + ob + r * 64 + c0 + 4, *(const f32x4*)&ofl[r * 72 + c0 + 4]);
      if (tid < 128) {
        int rr = tid >> 1, jj = tid & 1;
        const f32x4* wr4 = (const f32x4*)(wfcv + jj * 64);
        const f32x4* or4 = (const f32x4*)&ofl[rr * 72];
        f32x4 sv = (f32x4){0.f, 0.f, 0.f, 0.f};
        #pragma unroll
        for (int kk = 0; kk < 16; ++kk) sv += or4[kk] * wr4[kk];
        float s = bfcv[jj] + sv[0] + sv[1] + sv[2] + sv[3];
        size_t yi = ((size_t)t * BN + r0 + rr) * 2 + jj;
        __builtin_nontemporal_store(s, out_ys + yi);
        __builtin_nontemporal_store(jj ? cue1[rr] : cue0[rr], out_cue + yi);
      }
      size_t fb = ((size_t)t * BN + r0) * 256;   // 16384 floats per feed array
      f32x4 z = (f32x4){0.f, 0.f, 0.f, 0.f};
      #pragma unroll
      for (int s = 0; s < 8; ++s) {
        nt_st4(out_f1 + fb + (size_t)(s * 512 + tid) * 4, z);
        nt_st4(out_f2 + fb + (size_t)(s * 512 + tid) * 4, z);
      }
    }
    // no trailing barrier: bar0 of step t+1 fences ofl-vs-hscr reuse
  }

  // final h states
  for (int i = tid; i < 4096; i += 512) {
    int r = i >> 6, c0 = (i & 63) << 2;
    int li = r * 256 + (c0 ^ ((r & 7) << 3));
    size_t g = (size_t)(r0 + r) * 256 + c0;
    s16x4 s1 = *(const s16x4*)&h1s[li];
    s16x4 s2 = *(const s16x4*)&h2s[li];
    s16x4 s3 = *(const s16x4*)&h3s[li];
    nt_st4(out_h1 + g, (f32x4){bf2f(s1[0]), bf2f(s1[1]), bf2f(s1[2]), bf2f(s1[3])});
    nt_st4(out_h2 + g, (f32x4){bf2f(s2[0]), bf2f(s2[1]), bf2f(s2[2]), bf2f(s2[3])});
    nt_st4(out_h3 + g, (f32x4){bf2f(s3[0]), bf2f(s3[1]), bf2f(s3[2]), bf2f(s3[3])});
  }
}

extern "C" void kernel_launch(void* const* d_in, const int* in_sizes, int n_in,
                              void* d_out, int out_size, void* d_ws, size_t ws_size,
                              hipStream_t stream) {
  const float* x   = (const float*)d_in[0];
  const float* cue = (const float*)d_in[1];
  const float* hc1 = (const float*)d_in[2];
  const float* hc2 = (const float*)d_in[3];
  const float* hc3 = (const float*)d_in[4];
  const float* hc4 = (const float*)d_in[5];
  PrepPtrs pp;
  pp.w1i = (const float*)d_in[6];  pp.b1i = (const float*)d_in[7];
  pp.w1h = (const float*)d_in[8];  pp.b1h = (const float*)d_in[9];
  pp.w1o = (const float*)d_in[10]; pp.bo1 = (const float*)d_in[11];
  pp.w2i = (const float*)d_in[12]; pp.b2i = (const float*)d_in[13];
  pp.w2h = (const float*)d_in[14]; pp.b2h = (const float*)d_in[15];
  pp.w2o = (const float*)d_in[16]; pp.bo2 = (const float*)d_in[17];
  pp.w3i = (const float*)d_in[18]; pp.b3i = (const float*)d_in[19];
  pp.w3h = (const float*)d_in[20]; pp.b3h = (const float*)d_in[21];
  pp.w3o = (const float*)d_in[22]; pp.bo3 = (const float*)d_in[23];
  pp.wfc = (const float*)d_in[24]; pp.bfc = (const float*)d_in[25];

  short* wpk   = (short*)d_ws;                       // 311296 bf16 = 622592 B
  float* wmisc = (float*)((char*)d_ws + 622592);     // 1602 f32

  prep_kernel<<<64, 256, 0, stream>>>(pp, wpk, wmisc);
  rnn_main<<<256, 512, 0, stream>>>(x, cue, hc1, hc2, hc3, hc4, wpk, wmisc, (float*)d_out);
}

// Round 14
// 524.455 us; speedup vs baseline: 2.3089x; 1.0765x over previous
//
#include <hip/hip_runtime.h>
#include <stdint.h>
#include <stddef.h>

// RNN_arch_2_final: 3-cell stacked RNN, T=16, B=16384, hidden 256.
// R14 = R13 + (a) x(t+1) prefetch issued at phase-D start, written to xls in
// phase E (HBM latency hides under D/E); (b) the two post-store barriers
// (loop-top, D->E) become lgkmcnt-only (their hazards are LDS-only; the
// vmcnt(0) drain of the NT feed/output store queue is skipped). All other
// barriers remain __syncthreads (R12 showed blanket BAR regresses).

#define BN 16384
#define TT 16

typedef short s16x8 __attribute__((ext_vector_type(8)));
typedef short s16x4 __attribute__((ext_vector_type(4)));
typedef float f32x4 __attribute__((ext_vector_type(4)));

#define MFMA(a, b, c) __builtin_amdgcn_mfma_f32_16x16x32_bf16((a), (b), (c), 0, 0, 0)
// LDS-ordering barrier WITHOUT vmcnt drain. Used ONLY where the protected
// hazard is LDS-only and heavy NT stores are in flight (loop-top, D->E).
#define BARL() asm volatile("s_waitcnt lgkmcnt(0)\n\ts_barrier" ::: "memory")

__device__ __forceinline__ short f2bf(float f) {
  union { float f; uint32_t u; } v; v.f = f;
  uint32_t u = v.u;
  u += 0x7FFFu + ((u >> 16) & 1u);   // RNE
  return (short)(u >> 16);
}
__device__ __forceinline__ float bf2f(short s) {
  union { uint32_t u; float f; } v; v.u = ((uint32_t)(uint16_t)s) << 16;
  return v.f;
}
__device__ __forceinline__ float fast_tanh(float xx) {
  float x = fminf(8.f, fmaxf(-8.f, xx));
  float e = __expf(2.f * x);
  return (e - 1.f) * __builtin_amdgcn_rcpf(e + 1.f);
}
__device__ __forceinline__ void nt_st4(float* p, f32x4 v) {
  __builtin_nontemporal_store(v, (f32x4*)p);
}
__device__ __forceinline__ f32x4 nt_ld4(const float* p) {
  return __builtin_nontemporal_load((const f32x4*)p);
}

struct PrepPtrs {
  const float *w1i, *w1h, *w1o, *w2i, *w2h, *w2o, *w3i, *w3h, *w3o;
  const float *b1i, *b1h, *b2i, *b2h, *b3i, *b3h, *bo1, *bo2, *bo3, *wfc, *bfc;
};

// Pack W[n][k] fragments: frag(kt,nt): elem(lane,e) = W[nt*16+(lane&15)][kt*32+(lane>>4)*8+e]
__global__ void prep_kernel(PrepPtrs pp, short* __restrict__ wpk, float* __restrict__ wmisc) {
  const float* P[9] = {pp.w1i, pp.w1h, pp.w1o, pp.w2i, pp.w2h, pp.w2o, pp.w3i, pp.w3h, pp.w3o};
  const int LD_[9] = {64, 256, 256, 64, 256, 256, 130, 256, 256};
  const int C0_[9] = {0, 0, 0, 0, 0, 0, 2, 0, 0};
  const int NT_[9] = {16, 16, 4, 16, 16, 4, 16, 16, 4};
  const int DO_[10] = {0, 16384, 81920, 98304, 114688, 180224, 196608, 229376, 294912, 311296};
  int stride = gridDim.x * blockDim.x;
  for (int g = blockIdx.x * blockDim.x + threadIdx.x; g < 311296; g += stride) {
    int m = 0;
    while (g >= DO_[m + 1]) ++m;
    int p = g - DO_[m];
    int NT = NT_[m];
    int frag = p >> 9, lane = (p >> 3) & 63, e = p & 7;
    int kt = frag / NT, nt = frag - kt * NT;
    int row = nt * 16 + (lane & 15);
    int col = kt * 32 + ((lane >> 4) << 3) + e;
    wpk[g] = f2bf(P[m][(size_t)row * LD_[m] + C0_[m] + col]);
  }
  for (int i = blockIdx.x * blockDim.x + threadIdx.x; i < 1602; i += stride) {
    float v;
    if      (i < 256)  v = pp.b1i[i]         + pp.b1h[i];
    else if (i < 512)  v = pp.b2i[i - 256]   + pp.b2h[i - 256];
    else if (i < 768)  v = pp.b3i[i - 512]   + pp.b3h[i - 512];
    else if (i < 832)  v = pp.bo1[i - 768];
    else if (i < 896)  v = pp.bo2[i - 832];
    else if (i < 960)  v = pp.bo3[i - 896];
    else if (i < 1088) v = pp.wfc[i - 960];
    else if (i < 1090) v = pp.bfc[i - 1088];
    else if (i < 1346) v = pp.w3i[(size_t)(i - 1090) * 130];
    else               v = pp.w3i[(size_t)(i - 1346) * 130 + 1];
    wmisc[i] = v;
  }
}

__launch_bounds__(512, 2)
__global__ void rnn_main(const float* __restrict__ x, const float* __restrict__ cue,
                         const float* __restrict__ hc1, const float* __restrict__ hc2,
                         const float* __restrict__ hc3, const float* __restrict__ hc4,
                         const short* __restrict__ wpk, const float* __restrict__ wmisc,
                         float* __restrict__ out) {
  // LDS pool. h tiles: element (r,c) at [r*256 + (c ^ ((r&7)<<3))].
  // Union (o12s+ofl | hscr): hscr live A1-epi..A2-epi; o12s/ofl written fresh
  // in B/D each step; loop-top barrier fences E(t-1) reads vs A1(t) writes.
  __shared__ __align__(16) char pool[141312];
  short* h1s  = (short*)pool;                    // 32768 B
  short* h2s  = (short*)(pool + 32768);          // 32768 B
  short* h3s  = (short*)(pool + 65536);          // 32768 B
  short* o12s = (short*)(pool + 98304);          // 16384 B  (union w/ hscr)
  float* ofl  = (float*)(pool + 114688);         // 18432 B  (union w/ hscr tail)
  short* hscr = (short*)(pool + 98304);          // 32768 B  scratch for h1new
  short* xls  = (short*)(pool + 133120);         // 8192 B   x tile (bf16, swz)
  __shared__ float cue0[64], cue1[64];
  __shared__ __align__(16) float misc[1604];

  const int tid = threadIdx.x;
  const int wv = tid >> 6;          // 0..7
  const int lane = tid & 63;
  const int lr = lane & 15;
  const int lq = lane >> 4;
  const int swz = (lr & 7) << 3;
  const int r0 = blockIdx.x * 64;

  float* out_ys  = out;
  float* out_h1  = out + 524288;
  float* out_h2  = out + 4718592;
  float* out_h3  = out + 8912896;
  float* out_h4  = out + 13107200;
  float* out_o1s = out + 17301504;
  float* out_o2s = out + 34078720;
  float* out_cue = out + 50855936;
  float* out_f1  = out + 51380224;
  float* out_f2  = out + 118489088;
  float* out_of  = out + 185597952;

  for (int i = tid; i < 1602; i += 512) misc[i] = wmisc[i];
  if (tid < 64) {
    float cv = cue[r0 + tid];
    cue0[tid] = cv * 10.f;
    cue1[tid] = 10.f * fabsf(cv - 1.f);
  }
  // stage initial h (f32 -> bf16, swizzled) + h4 passthrough
  for (int i = tid; i < 4096; i += 512) {
    int r = i >> 6, c0 = (i & 63) << 2;
    int li = r * 256 + (c0 ^ ((r & 7) << 3));
    size_t g = (size_t)(r0 + r) * 256 + c0;
    f32x4 v1 = __builtin_nontemporal_load((const f32x4*)(hc1 + g));
    f32x4 v2 = __builtin_nontemporal_load((const f32x4*)(hc2 + g));
    f32x4 v3 = __builtin_nontemporal_load((const f32x4*)(hc3 + g));
    f32x4 v4 = __builtin_nontemporal_load((const f32x4*)(hc4 + g));
    *(s16x4*)&h1s[li] = (s16x4){f2bf(v1.x), f2bf(v1.y), f2bf(v1.z), f2bf(v1.w)};
    *(s16x4*)&h2s[li] = (s16x4){f2bf(v2.x), f2bf(v2.y), f2bf(v2.z), f2bf(v2.w)};
    *(s16x4*)&h3s[li] = (s16x4){f2bf(v3.x), f2bf(v3.y), f2bf(v3.z), f2bf(v3.w)};
    nt_st4(out_h4 + g, v4);
  }
  // stage x(t=0) into xls (prologue)
  const int xr = tid >> 3, xcq = (tid & 7) << 3;
  {
    const float* px = x + ((size_t)(r0 + xr)) * 64 + xcq;
    f32x4 a0 = nt_ld4(px);
    f32x4 a1 = nt_ld4(px + 4);
    *(s16x8*)&xls[xr * 64 + (xcq ^ ((xr & 7) << 3))] =
        (s16x8){f2bf(a0.x), f2bf(a0.y), f2bf(a0.z), f2bf(a0.w),
                f2bf(a1.x), f2bf(a1.y), f2bf(a1.z), f2bf(a1.w)};
  }
  __syncthreads();

  const short* Wp1i  = wpk;
  const short* Wp1h  = wpk + 16384;
  const short* Wp1o  = wpk + 81920;
  const short* Wp2i  = wpk + 98304;
  const short* Wp2h  = wpk + 114688;
  const short* Wp2o  = wpk + 180224;
  const short* Wp3ab = wpk + 196608;
  const short* Wp3h  = wpk + 229376;
  const short* Wp3o  = wpk + 294912;
  const float* bh1v = misc;
  const float* bh2v = misc + 256;
  const float* bh3v = misc + 512;
  const float* bo1v = misc + 768;
  const float* bo2v = misc + 832;
  const float* bofv = misc + 896;
  const float* wfcv = misc + 960;
  const float* bfcv = misc + 1088;
  const float* w3c0 = misc + 1090;
  const float* w3c1 = misc + 1346;

  for (int t = 0; t < TT; ++t) {
    BARL();   // loop-top: fences E(t-1) ofl/xls activity vs A1 hscr writes.
              // LDS-only hazard -> no vmcnt drain (feed stores keep flowing).

    // ---------- Phase A1: cell 1 only (acc1 = 32 VGPRs live)
    {
      f32x4 acc1[4][2];
      #pragma unroll
      for (int j = 0; j < 2; ++j) {
        int nb = (2 * wv + j) * 16 + lq * 4;
        f32x4 b1 = *(const f32x4*)(bh1v + nb);
        #pragma unroll
        for (int rt = 0; rt < 4; ++rt) acc1[rt][j] = b1;
      }
      #pragma unroll
      for (int kt = 0; kt < 2; ++kt) {   // x part, K=64 (from LDS)
        s16x8 aw0 = *(const s16x8*)(Wp1i + ((size_t)(kt * 16 + 2 * wv) * 64 + lane) * 8);
        s16x8 aw1 = *(const s16x8*)(Wp1i + ((size_t)(kt * 16 + 2 * wv + 1) * 64 + lane) * 8);
        #pragma unroll
        for (int rt = 0; rt < 4; ++rt) {
          s16x8 xb = *(const s16x8*)&xls[(rt * 16 + lr) * 64 + ((kt * 32 + lq * 8) ^ swz)];
          acc1[rt][0] = MFMA(aw0, xb, acc1[rt][0]);
          acc1[rt][1] = MFMA(aw1, xb, acc1[rt][1]);
        }
      }
      #pragma unroll
      for (int kt = 0; kt < 8; ++kt) {   // recurrent, K=256
        s16x8 aw0 = *(const s16x8*)(Wp1h + ((size_t)(kt * 16 + 2 * wv) * 64 + lane) * 8);
        s16x8 aw1 = *(const s16x8*)(Wp1h + ((size_t)(kt * 16 + 2 * wv + 1) * 64 + lane) * 8);
        #pragma unroll
        for (int rt = 0; rt < 4; ++rt) {
          s16x8 hb = *(const s16x8*)&h1s[(rt * 16 + lr) * 256 + ((kt * 32 + lq * 8) ^ swz)];
          acc1[rt][0] = MFMA(aw0, hb, acc1[rt][0]);
          acc1[rt][1] = MFMA(aw1, hb, acc1[rt][1]);
        }
      }
      // epi: park tanh(acc1) in hscr (NOT h1s) - acc1 dies here
      #pragma unroll
      for (int j = 0; j < 2; ++j) {
        int cb = (2 * wv + j) * 16 + lq * 4;
        #pragma unroll
        for (int rt = 0; rt < 4; ++rt) {
          *(s16x4*)&hscr[(rt * 16 + lr) * 256 + (cb ^ swz)] =
              (s16x4){f2bf(fast_tanh(acc1[rt][j][0])), f2bf(fast_tanh(acc1[rt][j][1])),
                      f2bf(fast_tanh(acc1[rt][j][2])), f2bf(fast_tanh(acc1[rt][j][3]))};
        }
      }
    }

    // ---------- Phase A2: cell 2 (acc2 = 32 VGPRs live)
    {
      f32x4 acc2[4][2];
      #pragma unroll
      for (int j = 0; j < 2; ++j) {
        int nb = (2 * wv + j) * 16 + lq * 4;
        f32x4 b2 = *(const f32x4*)(bh2v + nb);
        #pragma unroll
        for (int rt = 0; rt < 4; ++rt) acc2[rt][j] = b2;
      }
      #pragma unroll
      for (int kt = 0; kt < 2; ++kt) {   // x part, K=64 (from LDS)
        s16x8 aw0 = *(const s16x8*)(Wp2i + ((size_t)(kt * 16 + 2 * wv) * 64 + lane) * 8);
        s16x8 aw1 = *(const s16x8*)(Wp2i + ((size_t)(kt * 16 + 2 * wv + 1) * 64 + lane) * 8);
        #pragma unroll
        for (int rt = 0; rt < 4; ++rt) {
          s16x8 xb = *(const s16x8*)&xls[(rt * 16 + lr) * 64 + ((kt * 32 + lq * 8) ^ swz)];
          acc2[rt][0] = MFMA(aw0, xb, acc2[rt][0]);
          acc2[rt][1] = MFMA(aw1, xb, acc2[rt][1]);
        }
      }
      #pragma unroll
      for (int kt = 0; kt < 8; ++kt) {   // recurrent, K=256
        s16x8 aw0 = *(const s16x8*)(Wp2h + ((size_t)(kt * 16 + 2 * wv) * 64 + lane) * 8);
        s16x8 aw1 = *(const s16x8*)(Wp2h + ((size_t)(kt * 16 + 2 * wv + 1) * 64 + lane) * 8);
        #pragma unroll
        for (int rt = 0; rt < 4; ++rt) {
          s16x8 hb = *(const s16x8*)&h2s[(rt * 16 + lr) * 256 + ((kt * 32 + lq * 8) ^ swz)];
          acc2[rt][0] = MFMA(aw0, hb, acc2[rt][0]);
          acc2[rt][1] = MFMA(aw1, hb, acc2[rt][1]);
        }
      }
      __syncthreads();   // bar2: h2s/xls reads done, hscr fully written
      // epi: write h2new in place; copy hscr -> h1s (linear 16B chunks)
      #pragma unroll
      for (int j = 0; j < 2; ++j) {
        int cb = (2 * wv + j) * 16 + lq * 4;
        #pragma unroll
        for (int rt = 0; rt < 4; ++rt) {
          *(s16x4*)&h2s[(rt * 16 + lr) * 256 + (cb ^ swz)] =
              (s16x4){f2bf(fast_tanh(acc2[rt][j][0])), f2bf(fast_tanh(acc2[rt][j][1])),
                      f2bf(fast_tanh(acc2[rt][j][2])), f2bf(fast_tanh(acc2[rt][j][3]))};
        }
      }
      #pragma unroll
      for (int i = 0; i < 4; ++i) {
        int e = (i * 512 + tid) * 8;
        *(s16x8*)&h1s[e] = *(const s16x8*)&hscr[e];
      }
      __syncthreads();   // bar3: h1s/h2s ready
    }

    // ---------- Phase B: o1 (waves 0-3) / o2 (waves 4-7)
    {
      int cell = wv >> 2, w4 = wv & 3;
      const short* hs = cell ? h2s : h1s;
      const short* Wo = cell ? Wp2o : Wp1o;
      const float* bo = cell ? bo2v : bo1v;
      int nb = w4 * 16 + lq * 4;
      f32x4 bb = *(const f32x4*)(bo + nb);
      f32x4 acc[4];
      #pragma unroll
      for (int rt = 0; rt < 4; ++rt) acc[rt] = bb;
      #pragma unroll
      for (int kt = 0; kt < 8; ++kt) {
        s16x8 aw = *(const s16x8*)(Wo + ((size_t)(kt * 4 + w4) * 64 + lane) * 8);
        #pragma unroll
        for (int rt = 0; rt < 4; ++rt) {
          s16x8 hb = *(const s16x8*)&hs[(rt * 16 + lr) * 256 + ((kt * 32 + lq * 8) ^ swz)];
          acc[rt] = MFMA(aw, hb, acc[rt]);
        }
      }
      int cb = cell * 64 + nb;
      #pragma unroll
      for (int rt = 0; rt < 4; ++rt) {
        *(s16x4*)&o12s[(rt * 16 + lr) * 128 + (cb ^ swz)] =
            (s16x4){f2bf(fast_tanh(acc[rt][0])), f2bf(fast_tanh(acc[rt][1])),
                    f2bf(fast_tanh(acc[rt][2])), f2bf(fast_tanh(acc[rt][3]))};
      }
    }
    __syncthreads();

    // ---------- Phase C: h3new
    {
      f32x4 acc3[4][2];
      #pragma unroll
      for (int j = 0; j < 2; ++j) {
        int nb = (2 * wv + j) * 16 + lq * 4;
        f32x4 bb  = *(const f32x4*)(bh3v + nb);
        f32x4 c0w = *(const f32x4*)(w3c0 + nb);
        f32x4 c1w = *(const f32x4*)(w3c1 + nb);
        #pragma unroll
        for (int rt = 0; rt < 4; ++rt) {
          float cz = cue0[rt * 16 + lr], co = cue1[rt * 16 + lr];
          acc3[rt][j] = bb + cz * c0w + co * c1w;
        }
      }
      #pragma unroll
      for (int kt = 0; kt < 4; ++kt) {   // [o1|o2], K=128
        s16x8 aw0 = *(const s16x8*)(Wp3ab + ((size_t)(kt * 16 + 2 * wv) * 64 + lane) * 8);
        s16x8 aw1 = *(const s16x8*)(Wp3ab + ((size_t)(kt * 16 + 2 * wv + 1) * 64 + lane) * 8);
        #pragma unroll
        for (int rt = 0; rt < 4; ++rt) {
          s16x8 ob = *(const s16x8*)&o12s[(rt * 16 + lr) * 128 + ((kt * 32 + lq * 8) ^ swz)];
          acc3[rt][0] = MFMA(aw0, ob, acc3[rt][0]);
          acc3[rt][1] = MFMA(aw1, ob, acc3[rt][1]);
        }
      }
      #pragma unroll
      for (int kt = 0; kt < 8; ++kt) {   // recurrent, K=256
        s16x8 aw0 = *(const s16x8*)(Wp3h + ((size_t)(kt * 16 + 2 * wv) * 64 + lane) * 8);
        s16x8 aw1 = *(const s16x8*)(Wp3h + ((size_t)(kt * 16 + 2 * wv + 1) * 64 + lane) * 8);
        #pragma unroll
        for (int rt = 0; rt < 4; ++rt) {
          s16x8 hb = *(const s16x8*)&h3s[(rt * 16 + lr) * 256 + ((kt * 32 + lq * 8) ^ swz)];
          acc3[rt][0] = MFMA(aw0, hb, acc3[rt][0]);
          acc3[rt][1] = MFMA(aw1, hb, acc3[rt][1]);
        }
      }
      __syncthreads();   // done reading old h3
      #pragma unroll
      for (int j = 0; j < 2; ++j) {
        int cb = (2 * wv + j) * 16 + lq * 4;
        #pragma unroll
        for (int rt = 0; rt < 4; ++rt) {
          *(s16x4*)&h3s[(rt * 16 + lr) * 256 + (cb ^ swz)] =
              (s16x4){f2bf(fast_tanh(acc3[rt][j][0])), f2bf(fast_tanh(acc3[rt][j][1])),
                      f2bf(fast_tanh(acc3[rt][j][2])), f2bf(fast_tanh(acc3[rt][j][3]))};
        }
      }
      __syncthreads();
    }

    // ---------- x(t+1) prefetch: issue loads now (latency hides under D/E)
    int tn = (t + 1 < TT) ? (t + 1) : t;
    const float* pxn = x + ((size_t)tn * BN + r0 + xr) * 64 + xcq;
    f32x4 xa0 = nt_ld4(pxn);
    f32x4 xa1 = nt_ld4(pxn + 4);

    // ---------- Phase D: waves 0-3 compute of; waves 4-7 store o1s/o2s (NT)
    if (wv < 4) {
      int nb = wv * 16 + lq * 4;
      f32x4 bb = *(const f32x4*)(bofv + nb);
      f32x4 acc[4];
      #pragma unroll
      for (int rt = 0; rt < 4; ++rt) acc[rt] = bb;
      #pragma unroll
      for (int kt = 0; kt < 8; ++kt) {
        s16x8 aw = *(const s16x8*)(Wp3o + ((size_t)(kt * 4 + wv) * 64 + lane) * 8);
        #pragma unroll
        for (int rt = 0; rt < 4; ++rt) {
          s16x8 hb = *(const s16x8*)&h3s[(rt * 16 + lr) * 256 + ((kt * 32 + lq * 8) ^ swz)];
          acc[rt] = MFMA(aw, hb, acc[rt]);
        }
      }
      #pragma unroll
      for (int rt = 0; rt < 4; ++rt) {
        f32x4 v = (f32x4){fmaxf(0.f, acc[rt][0]), fmaxf(0.f, acc[rt][1]),
                          fmaxf(0.f, acc[rt][2]), fmaxf(0.f, acc[rt][3])};
        *(f32x4*)&ofl[(rt * 16 + lr) * 72 + nb] = v;
      }
    } else {
      size_t ob = ((size_t)t * BN + r0) * 64;
      float* targ = (wv < 6) ? out_o1s : out_o2s;
      int coff = (wv < 6) ? 0 : 64;
      int wq = wv & 1;
      #pragma unroll
      for (int s = 0; s < 8; ++s) {
        int f = wq * 2048 + s * 256 + lane * 4;
        int r = f >> 6, c = f & 63;
        s16x4 v = *(const s16x4*)&o12s[r * 128 + ((c + coff) ^ ((r & 7) << 3))];
        nt_st4(targ + ob + f, (f32x4){bf2f(v[0]), bf2f(v[1]), bf2f(v[2]), bf2f(v[3])});
      }
    }
    BARL();   // D->E: hazard is ofl (LDS) only; skip the NT-store drain

    // ---------- Phase E: of store + y + cue_arr + feed zero-fill (NT)
    //            + xls(t+1) write (fenced vs A1(t+1) by loop-top BARL)
    {
      size_t ob = ((size_t)t * BN + r0) * 64;
      int r = tid >> 3, c0 = (tid & 7) << 3;
      nt_st4(out_of + ob + r * 64 + c0,     *(const f32x4*)&ofl[r * 72 + c0]);
      nt_st4(out_of + ob + r * 64 + c0 + 4, *(const f32x4*)&ofl[r * 72 + c0 + 4]);
      *(s16x8*)&xls[xr * 64 + (xcq ^ ((xr & 7) << 3))] =
          (s16x8){f2bf(xa0.x), f2bf(xa0.y), f2bf(xa0.z), f2bf(xa0.w),
                  f2bf(xa1.x), f2bf(xa1.y), f2bf(xa1.z), f2bf(xa1.w)};
      if (tid < 128) {
        int rr = tid >> 1, jj = tid & 1;
        const f32x4* wr4 = (const f32x4*)(wfcv + jj * 64);
        const f32x4* or4 = (const f32x4*)&ofl[rr * 72];
        f32x4 sv = (f32x4){0.f, 0.f, 0.f, 0.f};
        #pragma unroll
        for (int kk = 0; kk < 16; ++kk) sv += or4[kk] * wr4[kk];
        float s = bfcv[jj] + sv[0] + sv[1] + sv[2] + sv[3];
        size_t yi = ((size_t)t * BN + r0 + rr) * 2 + jj;
        __builtin_nontemporal_store(s, out_ys + yi);
        __builtin_nontemporal_store(jj ? cue1[rr] : cue0[rr], out_cue + yi);
      }
      size_t fb = ((size_t)t * BN + r0) * 256;   // 16384 floats per feed array
      f32x4 z = (f32x4){0.f, 0.f, 0.f, 0.f};
      #pragma unroll
      for (int s = 0; s < 8; ++s) {
        nt_st4(out_f1 + fb + (size_t)(s * 512 + tid) * 4, z);
        nt_st4(out_f2 + fb + (size_t)(s * 512 + tid) * 4, z);
      }
    }
    // loop-top BARL() of step t+1 fences ofl-vs-hscr reuse and xls handoff
  }

  // final h states
  for (int i = tid; i < 4096; i += 512) {
    int r = i >> 6, c0 = (i & 63) << 2;
    int li = r * 256 + (c0 ^ ((r & 7) << 3));
    size_t g = (size_t)(r0 + r) * 256 + c0;
    s16x4 s1 = *(const s16x4*)&h1s[li];
    s16x4 s2 = *(const s16x4*)&h2s[li];
    s16x4 s3 = *(const s16x4*)&h3s[li];
    nt_st4(out_h1 + g, (f32x4){bf2f(s1[0]), bf2f(s1[1]), bf2f(s1[2]), bf2f(s1[3])});
    nt_st4(out_h2 + g, (f32x4){bf2f(s2[0]), bf2f(s2[1]), bf2f(s2[2]), bf2f(s2[3])});
    nt_st4(out_h3 + g, (f32x4){bf2f(s3[0]), bf2f(s3[1]), bf2f(s3[2]), bf2f(s3[3])});
  }
}

extern "C" void kernel_launch(void* const* d_in, const int* in_sizes, int n_in,
                              void* d_out, int out_size, void* d_ws, size_t ws_size,
                              hipStream_t stream) {
  const float* x   = (const float*)d_in[0];
  const float* cue = (const float*)d_in[1];
  const float* hc1 = (const float*)d_in[2];
  const float* hc2 = (const float*)d_in[3];
  const float* hc3 = (const float*)d_in[4];
  const float* hc4 = (const float*)d_in[5];
  PrepPtrs pp;
  pp.w1i = (const float*)d_in[6];  pp.b1i = (const float*)d_in[7];
  pp.w1h = (const float*)d_in[8];  pp.b1h = (const float*)d_in[9];
  pp.w1o = (const float*)d_in[10]; pp.bo1 = (const float*)d_in[11];
  pp.w2i = (const float*)d_in[12]; pp.b2i = (const float*)d_in[13];
  pp.w2h = (const float*)d_in[14]; pp.b2h = (const float*)d_in[15];
  pp.w2o = (const float*)d_in[16]; pp.bo2 = (const float*)d_in[17];
  pp.w3i = (const float*)d_in[18]; pp.b3i = (const float*)d_in[19];
  pp.w3h = (const float*)d_in[20]; pp.b3h = (const float*)d_in[21];
  pp.w3o = (const float*)d_in[22]; pp.bo3 = (const float*)d_in[23];
  pp.wfc = (const float*)d_in[24]; pp.bfc = (const float*)d_in[25];

  short* wpk   = (short*)d_ws;                       // 311296 bf16 = 622592 B
  float* wmisc = (float*)((char*)d_ws + 622592);     // 1602 f32

  prep_kernel<<<64, 256, 0, stream>>>(pp, wpk, wmisc);
  rnn_main<<<256, 512, 0, stream>>>(x, cue, hc1, hc2, hc3, hc4, wpk, wmisc, (float*)d_out);
}